// Round 11
// baseline (540.140 us; speedup 1.0000x reference)
//
#include <hip/hip_runtime.h>
#include <cstdint>
#include <cstddef>

#define EDIM 256
#define VDIM 8192
#define NPIX 16384
#define QCAP 448

typedef __attribute__((ext_vector_type(8))) short          bf16x8;
typedef __attribute__((ext_vector_type(8))) unsigned short u16x8;
typedef __attribute__((ext_vector_type(4))) float          f32x4;
typedef __attribute__((ext_vector_type(2))) float          f32x2;

// RNE float->bf16
__device__ __forceinline__ unsigned short f2bf(float x) {
    unsigned int u = __float_as_uint(x);
    return (unsigned short)((u + 0x7fffu + ((u >> 16) & 1u)) >> 16);
}

__device__ __forceinline__ void gload_lds16(const void* gsrc, void* ldst) {
#if defined(__has_builtin) && __has_builtin(__builtin_amdgcn_global_load_lds)
    __builtin_amdgcn_global_load_lds(
        (const __attribute__((address_space(1))) unsigned int*)gsrc,
        (__attribute__((address_space(3))) unsigned int*)ldst, 16, 0, 0);
#else
    *(float4*)ldst = *(const float4*)gsrc;
#endif
}

// ---------- numpy pairwise sum-of-squares (exact semantics, verified r2) ----------
__device__ __forceinline__ float np_sqpair128(const float* __restrict__ z) {
    float r[8];
#pragma unroll
    for (int j = 0; j < 8; ++j) r[j] = __fmul_rn(z[j], z[j]);
    for (int i = 8; i < 128; i += 8) {
#pragma unroll
        for (int j = 0; j < 8; ++j)
            r[j] = __fadd_rn(r[j], __fmul_rn(z[i + j], z[i + j]));
    }
    float t01 = __fadd_rn(r[0], r[1]), t23 = __fadd_rn(r[2], r[3]);
    float t45 = __fadd_rn(r[4], r[5]), t67 = __fadd_rn(r[6], r[7]);
    return __fadd_rn(__fadd_rn(t01, t23), __fadd_rn(t45, t67));
}

// ---------------- Stage 1 (FUSED): z32 + zbf frags + A32 + thr ----------------
__global__ __launch_bounds__(256) void pre_quant_fused(const float* __restrict__ x,
                                                       const float* __restrict__ Wpre,
                                                       const float* __restrict__ bpre,
                                                       float* __restrict__ z32,
                                                       unsigned short* __restrict__ zbf,
                                                       float* __restrict__ A32,
                                                       float* __restrict__ thr) {
#pragma clang fp contract(off)
    __shared__ float xs[32][36];
    __shared__ float wt[32][260];   // [c][e]; aliased as zs[32][260] in epilogue
    int n0 = blockIdx.x * 32;
    int b = n0 >> 8, pix0 = n0 & 255;
    int t = threadIdx.x;
    int ep = t & 31, pg = t >> 5;

    f32x2 acc[4][4];
#pragma unroll
    for (int pi = 0; pi < 4; ++pi)
#pragma unroll
        for (int j = 0; j < 4; ++j) acc[pi][j] = (f32x2){0.f, 0.f};

    for (int c0 = 0; c0 < 256; c0 += 32) {
        __syncthreads();
        {   int cc = t >> 3, pp = (t & 7) * 4;
            *(float4*)&xs[cc][pp] =
                *(const float4*)&x[(size_t)b * 65536 + (size_t)(c0 + cc) * 256 + pix0 + pp];
        }
        {   const float* wr = Wpre + (size_t)t * 256 + c0;
#pragma unroll
            for (int i = 0; i < 32; i += 4) {
                float4 v = *(const float4*)&wr[i];
                wt[i + 0][t] = v.x; wt[i + 1][t] = v.y;
                wt[i + 2][t] = v.z; wt[i + 3][t] = v.w;
            }
        }
        __syncthreads();
#pragma unroll 8
        for (int cc = 0; cc < 32; ++cc) {
            float4 xv = *(const float4*)&xs[cc][pg * 4];
            float xa[4] = {xv.x, xv.y, xv.z, xv.w};
            f32x2 wv[4];
#pragma unroll
            for (int j = 0; j < 4; ++j) wv[j] = *(const f32x2*)&wt[cc][2 * ep + 64 * j];
#pragma unroll
            for (int pi = 0; pi < 4; ++pi) {
                f32x2 xsp = {xa[pi], xa[pi]};
#pragma unroll
                for (int j = 0; j < 4; ++j) {
                    f32x2 m = wv[j] * xsp;       // pk_mul (rounded)
                    acc[pi][j] = acc[pi][j] + m;  // pk_add (rounded) — contract off
                }
            }
        }
    }
    __syncthreads();   // all wt reads done before aliasing writes
    float* zs = &wt[0][0];   // [32][260]
    f32x2 b2[4];
#pragma unroll
    for (int j = 0; j < 4; ++j) b2[j] = *(const f32x2*)&bpre[2 * ep + 64 * j];
#pragma unroll
    for (int pi = 0; pi < 4; ++pi) {
        int row = pg * 4 + pi;
#pragma unroll
        for (int j = 0; j < 4; ++j) {
            f32x2 o = acc[pi][j] + b2[j];
            *(f32x2*)&z32[(size_t)(n0 + row) * 256 + 2 * ep + 64 * j] = o;
            *(f32x2*)&zs[row * 260 + 2 * ep + 64 * j] = o;
        }
    }
    __syncthreads();
#pragma unroll
    for (int q = 0; q < 4; ++q) {
        int uid = q * 256 + t;
        int l = uid & 63, ks = (uid >> 6) & 7, tile = uid >> 9;
        int rowl = tile * 16 + (l & 15), colb = ks * 32 + (l >> 4) * 8;
        const float* s = &zs[rowl * 260 + colb];
        float4 a = *(const float4*)s, bb = *(const float4*)(s + 4);
        u16x8 o;
        o[0] = f2bf(a.x); o[1] = f2bf(a.y); o[2] = f2bf(a.z); o[3] = f2bf(a.w);
        o[4] = f2bf(bb.x); o[5] = f2bf(bb.y); o[6] = f2bf(bb.z); o[7] = f2bf(bb.w);
        *((u16x8*)zbf + (((size_t)((n0 >> 4) + tile) * 8 + ks) * 64 + l)) = o;
    }
    if (t < 32) {
        float a = __fadd_rn(np_sqpair128(&zs[t * 260]), np_sqpair128(&zs[t * 260 + 128]));
        A32[n0 + t] = a;
        thr[n0 + t] = 2.75f * sqrtf(a) * 7.0466e-5f - 1e-6f;
    }
}

// ---------------- cb norms (np pairwise semantics) ----------------
__global__ __launch_bounds__(256) void cb_norms(const float* __restrict__ cb,
                                                float* __restrict__ C32) {
    int v = blockIdx.x * 256 + threadIdx.x;
    const float* r = cb + (size_t)v * 256;
    C32[v] = __fadd_rn(np_sqpair128(r), np_sqpair128(r + 128));
}

// ---------------- fragment-layout bf16 builder (codebook) ----------------
__global__ __launch_bounds__(256) void build_frag(const float* __restrict__ src,
                                                  unsigned short* __restrict__ dst) {
    int gid = blockIdx.x * 256 + threadIdx.x;
    int l = gid & 63, ks = (gid >> 6) & 7, tile = gid >> 9;
    int row = tile * 16 + (l & 15);
    int k = ks * 32 + (l >> 4) * 8;
    const float* s = src + (size_t)row * 256 + k;
    float4 a = *(const float4*)s, b = *(const float4*)(s + 4);
    u16x8 o;
    o[0] = f2bf(a.x); o[1] = f2bf(a.y); o[2] = f2bf(a.z); o[3] = f2bf(a.w);
    o[4] = f2bf(b.x); o[5] = f2bf(b.y); o[6] = f2bf(b.z); o[7] = f2bf(b.w);
    *((u16x8*)dst + gid) = o;
}

// ---------------- Stage 2: MFMA screen v6 (2 blocks/CU, LDS-atomic append) ----------------
// r10 post-mortem: 144 KB LDS -> 1 block/CU -> per-phase vmcnt drain fully exposed;
// 32 ballot+mbcnt chains per vt for ~3 rare fires -> 26% VALU. v6: 32 KB phases
// (dbuf 64 KB) + QCAP 448 -> 78 KB -> 2 blocks/CU; append via per-wave LDS atomicAdd
// (only firing lanes execute it). Queue order changes; rerank min is order-independent.
__global__ __launch_bounds__(512, 4) void screen(const unsigned short* __restrict__ zbf,
                                                 const unsigned short* __restrict__ cbf,
                                                 const float* __restrict__ C32,
                                                 const float* __restrict__ thr,
                                                 int* __restrict__ cnt,
                                                 int* __restrict__ cand) {
    __shared__ __align__(16) char lds[2][32768];
    __shared__ unsigned q[8][QCAP];   // 14 KiB per-wave candidate queues
    __shared__ int wq[8];
    int t = threadIdx.x, w = t >> 6, l = t & 63;
    int bid = blockIdx.x;
    int x = bid & 7, k = bid >> 3;
    int rowblk = (x & 3) * 8 + (k & 7);
    int vblk   = (x >> 2) * 4 + (k >> 3);
    int rb = rowblk * 512 + w * 64;

    const char* cbase = (const char*)cbf + (size_t)vblk * 524288;
    {   // issue phase-0 staging (32 KB) first so it overlaps the zf loads below
#pragma unroll
        for (int qq = 0; qq < 4; ++qq)
            gload_lds16(cbase + qq * 8192 + t * 16, &lds[0][0] + qq * 8192 + t * 16);
    }

    bf16x8 zf[4][8];
#pragma unroll
    for (int tt = 0; tt < 4; ++tt)
#pragma unroll
        for (int ks = 0; ks < 8; ++ks) {
            zf[tt][ks] = *((const bf16x8*)zbf + (((size_t)((rb >> 4) + tt) * 8 + ks) * 64 + l));
            asm volatile("" : "+a"(zf[tt][ks]));
        }

    int   rown[4];
    float thrv[4];
#pragma unroll
    for (int tt = 0; tt < 4; ++tt) {
        rown[tt] = rb + tt * 16 + (l & 15);
        thrv[tt] = thr[rown[tt]];
    }
    if (t < 8) wq[t] = 0;
    __syncthreads();

    for (int p = 0; p < 16; ++p) {
        int cur = p & 1;
        if (p < 15) {
            const char* src = cbase + (size_t)(p + 1) * 32768;
            char* dst = &lds[cur ^ 1][0];
#pragma unroll
            for (int qq = 0; qq < 4; ++qq)
                gload_lds16(src + qq * 8192 + t * 16, dst + qq * 8192 + t * 16);
        }
        const char* buf = &lds[cur][0];
#pragma unroll 2
        for (int vt = 0; vt < 4; ++vt) {
            f32x4 acc[4];
#pragma unroll
            for (int tt = 0; tt < 4; ++tt) acc[tt] = (f32x4){0.f, 0.f, 0.f, 0.f};
#pragma unroll
            for (int ks = 0; ks < 8; ++ks) {
                bf16x8 af = *(const bf16x8*)(buf + vt * 8192 + ks * 1024 + l * 16);
#pragma unroll
                for (int tt = 0; tt < 4; ++tt)
                    acc[tt] = __builtin_amdgcn_mfma_f32_16x16x32_bf16(af, zf[tt][ks], acc[tt], 0, 0, 0);
            }
            int v0 = vblk * 1024 + p * 64 + vt * 16 + (l >> 4) * 4;
            float4 c4 = *(const float4*)&C32[v0];
            float cv[4] = {c4.x, c4.y, c4.z, c4.w};
#pragma unroll
            for (int tt = 0; tt < 4; ++tt)
#pragma unroll
                for (int j = 0; j < 4; ++j) {
                    float s = __fmaf_rn(-0.5f, cv[j], acc[tt][j]);
                    if (s > thrv[tt]) {   // rare (~0.3% of checks)
                        int slot = atomicAdd(&wq[w], 1);   // LDS atomic, wave-private
                        unsigned pk = ((unsigned)rown[tt] << 13) | (unsigned)(v0 + j);
                        if (slot < QCAP) q[w][slot] = pk;
                        else {   // astronomically rare overflow: direct append
                            int sl = atomicAdd(&cnt[rown[tt]], 1);
                            if (sl < 64) cand[(size_t)rown[tt] * 64 + sl] = v0 + j;
                        }
                    }
                }
        }
        __syncthreads();
    }

    // per-wave flush: queue -> global (atomic latency exposed once, not per fire)
    int nq = wq[w] < QCAP ? wq[w] : QCAP;
    for (int i = l; i < nq; i += 64) {
        unsigned pk = q[w][i];
        int row = pk >> 13, v = pk & 8191;
        int sl = atomicAdd(&cnt[row], 1);
        if (sl < 64) cand[(size_t)row * 64 + sl] = v;
    }
}

// ---------------- Stage 3: exact np-f32 re-rank v3 ([k][item] LDS, reg-prefetch) ----------------
// r10 post-mortem: 74 KB LDS -> 2 blocks/CU, stride-65 [item][k] reads = 3.2M bank
// conflicts, 8 serial sync+stage rounds exposed. v3: 8 rows/block; [k][item] layout
// (compute reads sbuf[k][t] -> consecutive banks, conflict-free; 265 pad -> ~2-way
// writes); single 34 KB chunk buffer + 8xfloat4 register prefetch (next chunk loads
// issued before current chunk compute); ~48 KB -> 3 blocks/CU. FMA chain strictly
// ascending k (r2-verified) -> tokens bit-identical.
__global__ __launch_bounds__(256, 3) void rerank(const float* __restrict__ z32,
                                                 const float* __restrict__ cb,
                                                 const float* __restrict__ A32,
                                                 const float* __restrict__ C32,
                                                 const int* __restrict__ cand,
                                                 const int* __restrict__ cnt,
                                                 int* __restrict__ tok_i,
                                                 float* __restrict__ tok_f) {
    __shared__ float    sbuf[32][265];   // [k][item], 33.9 KB
    __shared__ float    zs[8][264];      // z rows, 8.4 KB
    __shared__ unsigned sv[512];         // packed (row<<13)|v
    __shared__ int      sh[9];
    __shared__ float    dbuf[8][64];
    __shared__ int      vbuf[8][64];
    int t = threadIdx.x;
    int n0 = blockIdx.x * 8;

    if (t == 0) {
        int o = 0;
#pragma unroll
        for (int r = 0; r < 8; ++r) {
            sh[r] = o;
            int n = cnt[n0 + r]; if (n > 64) n = 64;
            o += n;
        }
        sh[8] = o;
    }
    {   // stage z rows (coalesced) + init result slots
        int r = t >> 5, e = (t & 31) * 8;
        const float* zr = &z32[(size_t)(n0 + r) * 256 + e];
        *(float4*)&zs[r][e]     = *(const float4*)zr;
        *(float4*)&zs[r][e + 4] = *(const float4*)(zr + 4);
        int sl = t & 31;
        dbuf[r][sl] = 3.4e38f;      dbuf[r][sl + 32] = 3.4e38f;
        vbuf[r][sl] = 0x7fffffff;   vbuf[r][sl + 32] = 0x7fffffff;
    }
    __syncthreads();
    int m = sh[8];

    for (int i = t; i < m; i += 256) {
        int r = 0;
#pragma unroll
        for (int j = 1; j < 8; ++j) r += (i >= sh[j]);
        unsigned v = (unsigned)cand[(size_t)(n0 + r) * 64 + (i - sh[r])];
        sv[i] = ((unsigned)r << 13) | v;
    }
    __syncthreads();

    for (int b0 = 0; b0 < m; b0 += 256) {
        int mb = m - b0; if (mb > 256) mb = 256;
        bool act = t < mb;
        unsigned pk = act ? sv[b0 + t] : 0;
        int myrow = pk >> 13, myv = pk & 8191;
        float s = 0.0f;

        // stage unit mapping: 8-lane group per item, 128B contiguous per chunk:
        // item i = j*32 + (t>>3), quad q = t&7
        float4 pf[8];
#pragma unroll
        for (int j = 0; j < 8; ++j) {
            int i = j * 32 + (t >> 3);
            if (i < mb) {
                unsigned vv = sv[b0 + i] & 8191u;
                pf[j] = *(const float4*)&cb[(size_t)vv * 256 + (t & 7) * 4];
            }
        }
        for (int c = 0; c < 8; ++c) {
            __syncthreads();   // prior chunk's sbuf reads complete
#pragma unroll
            for (int j = 0; j < 8; ++j) {
                int i = j * 32 + (t >> 3);
                if (i < mb) {
                    int kb = (t & 7) * 4;
                    sbuf[kb + 0][i] = pf[j].x; sbuf[kb + 1][i] = pf[j].y;
                    sbuf[kb + 2][i] = pf[j].z; sbuf[kb + 3][i] = pf[j].w;
                }
            }
            __syncthreads();
            if (c < 7) {   // issue next chunk's loads; latency hides under compute
#pragma unroll
                for (int j = 0; j < 8; ++j) {
                    int i = j * 32 + (t >> 3);
                    if (i < mb) {
                        unsigned vv = sv[b0 + i] & 8191u;
                        pf[j] = *(const float4*)&cb[(size_t)vv * 256 + (c + 1) * 32 + (t & 7) * 4];
                    }
                }
            }
            if (act) {
                const float* zz = &zs[myrow][c * 32];
#pragma unroll
                for (int k = 0; k < 32; ++k)
                    s = __fmaf_rn(sbuf[k][t], zz[k], s);   // ascending k (r2 chain)
            }
        }
        if (act) {
            float d = __fadd_rn(__fsub_rn(A32[n0 + myrow], __fmul_rn(2.0f, s)), C32[myv]);
            int slot = (b0 + t) - sh[myrow];
            dbuf[myrow][slot] = d;
            vbuf[myrow][slot] = myv;
        }
    }
    __syncthreads();
    {   // per-row argmin: 32 threads per row
        int r = t >> 5, l5 = t & 31;
        float d1 = dbuf[r][l5], d2 = dbuf[r][l5 + 32];
        int   v1 = vbuf[r][l5], v2 = vbuf[r][l5 + 32];
        if (d2 < d1 || (d2 == d1 && v2 < v1)) { d1 = d2; v1 = v2; }
#pragma unroll
        for (int off = 16; off > 0; off >>= 1) {
            float dd = __shfl_xor(d1, off, 32);
            int   vv = __shfl_xor(v1, off, 32);
            if (dd < d1 || (dd == d1 && vv < v1)) { d1 = dd; v1 = vv; }
        }
        if (l5 == 0) { tok_i[n0 + r] = v1; tok_f[n0 + r] = (float)v1; }
    }
}

// ---------------- Stage 4: rec = codebook[tok] @ W_post^T + b_post ----------------
__global__ __launch_bounds__(256) void post_quant(const float* __restrict__ cb,
                                                  const float* __restrict__ Wpost,
                                                  const float* __restrict__ bpost,
                                                  const int* __restrict__ tok,
                                                  float* __restrict__ rec) {
    __shared__ float zq[256][36];   // [e][pix]
    __shared__ float wt[32][260];   // [e-chunk][cout]
    int n0 = blockIdx.x * 32;
    int b = n0 >> 8, pix0 = n0 & 255;
    int t = threadIdx.x;
    int ep = t & 31, pg = t >> 5;

    {   int pix = t & 31, eg = t >> 5;
        int tv = tok[n0 + pix];
        const float* cr = cb + (size_t)tv * 256 + eg * 32;
#pragma unroll
        for (int i = 0; i < 32; ++i)
            zq[eg * 32 + i][pix] = cr[i];
    }

    f32x2 acc[8][2];
#pragma unroll
    for (int s = 0; s < 8; ++s) { acc[s][0] = (f32x2){0.f, 0.f}; acc[s][1] = (f32x2){0.f, 0.f}; }

    for (int e0 = 0; e0 < 256; e0 += 32) {
        __syncthreads();
        const float* wr = Wpost + (size_t)t * 256 + e0;
#pragma unroll
        for (int i = 0; i < 32; i += 4) {
            float4 v = *(const float4*)&wr[i];
            wt[i + 0][t] = v.x; wt[i + 1][t] = v.y;
            wt[i + 2][t] = v.z; wt[i + 3][t] = v.w;
        }
        __syncthreads();
#pragma unroll 8
        for (int ee = 0; ee < 32; ++ee) {
            float4 zv = *(const float4*)&zq[e0 + ee][pg * 4];
            f32x2 zp0 = {zv.x, zv.y}, zp1 = {zv.z, zv.w};
#pragma unroll
            for (int J = 0; J < 4; ++J) {
                f32x2 wv = *(const f32x2*)&wt[ee][2 * ep + 64 * J];
                f32x2 w0 = {wv[0], wv[0]}, w1 = {wv[1], wv[1]};
                acc[2 * J + 0][0] = w0 * zp0 + acc[2 * J + 0][0];
                acc[2 * J + 0][1] = w0 * zp1 + acc[2 * J + 0][1];
                acc[2 * J + 1][0] = w1 * zp0 + acc[2 * J + 1][0];
                acc[2 * J + 1][1] = w1 * zp1 + acc[2 * J + 1][1];
            }
        }
    }
#pragma unroll
    for (int J = 0; J < 4; ++J)
#pragma unroll
        for (int c01 = 0; c01 < 2; ++c01) {
            int cout = 2 * ep + 64 * J + c01;
            float bv = bpost[cout];
            f32x2 bs = {bv, bv};
            f32x2 o0 = acc[2 * J + c01][0] + bs, o1 = acc[2 * J + c01][1] + bs;
            float4 ov = {o0[0], o0[1], o1[0], o1[1]};
            *(float4*)&rec[(size_t)b * 65536 + (size_t)cout * 256 + pix0 + pg * 4] = ov;
        }
}

// ---------------- Launch ----------------
extern "C" void kernel_launch(void* const* d_in, const int* in_sizes, int n_in,
                              void* d_out, int out_size, void* d_ws, size_t ws_size,
                              hipStream_t stream) {
    const float* x     = (const float*)d_in[0];
    const float* Wpre  = (const float*)d_in[1];
    const float* bpre  = (const float*)d_in[2];
    const float* cb    = (const float*)d_in[3];
    const float* Wpost = (const float*)d_in[4];
    const float* bpost = (const float*)d_in[5];

    float* out   = (float*)d_out;
    float* rec   = out;
    float* tok_f = out + 4194304;
    float* z32   = rec;   // z lives in rec region until post_quant overwrites it

    char* ws = (char*)d_ws;
    float*          A32   = (float*)(ws + 0);         // 64 KiB
    float*          C32   = (float*)(ws + 65536);     // 32 KiB
    int*            tok_i = (int*)(ws + 98304);       // 64 KiB
    float*          thr   = (float*)(ws + 163840);    // 64 KiB
    int*            cnt   = (int*)(ws + 229376);      // 64 KiB
    int*            cand  = (int*)(ws + 294912);      // 4 MiB
    unsigned short* zbf   = (unsigned short*)(ws + 4489216);   // 8 MiB
    unsigned short* cbf   = (unsigned short*)(ws + 12877824);  // 4 MiB

    pre_quant_fused<<<NPIX / 32, 256, 0, stream>>>(x, Wpre, bpre, z32, zbf, A32, thr);
    cb_norms<<<VDIM / 256, 256, 0, stream>>>(cb, C32);
    build_frag<<<(VDIM / 16) * 8 * 64 / 256, 256, 0, stream>>>(cb, cbf);
    hipMemsetAsync(cnt, 0, NPIX * sizeof(int), stream);
    screen<<<256, 512, 0, stream>>>(zbf, cbf, C32, thr, cnt, cand);
    rerank<<<NPIX / 8, 256, 0, stream>>>(z32, cb, A32, C32, cand, cnt, tok_i, tok_f);
    post_quant<<<NPIX / 32, 256, 0, stream>>>(cb, Wpost, bpost, tok_i, rec);
}

// Round 12
// 274.650 us; speedup vs baseline: 1.9666x; 1.9666x over previous
//
#include <hip/hip_runtime.h>
#include <cstdint>
#include <cstddef>

#define EDIM 256
#define VDIM 8192
#define NPIX 16384
#define QCAP 512

typedef __attribute__((ext_vector_type(8))) short          bf16x8;
typedef __attribute__((ext_vector_type(8))) unsigned short u16x8;
typedef __attribute__((ext_vector_type(4))) float          f32x4;
typedef __attribute__((ext_vector_type(2))) float          f32x2;

// RNE float->bf16
__device__ __forceinline__ unsigned short f2bf(float x) {
    unsigned int u = __float_as_uint(x);
    return (unsigned short)((u + 0x7fffu + ((u >> 16) & 1u)) >> 16);
}

__device__ __forceinline__ void gload_lds16(const void* gsrc, void* ldst) {
#if defined(__has_builtin) && __has_builtin(__builtin_amdgcn_global_load_lds)
    __builtin_amdgcn_global_load_lds(
        (const __attribute__((address_space(1))) unsigned int*)gsrc,
        (__attribute__((address_space(3))) unsigned int*)ldst, 16, 0, 0);
#else
    *(float4*)ldst = *(const float4*)gsrc;
#endif
}

// ---------- numpy pairwise sum-of-squares (exact semantics, verified r2) ----------
__device__ __forceinline__ float np_sqpair128(const float* __restrict__ z) {
    float r[8];
#pragma unroll
    for (int j = 0; j < 8; ++j) r[j] = __fmul_rn(z[j], z[j]);
    for (int i = 8; i < 128; i += 8) {
#pragma unroll
        for (int j = 0; j < 8; ++j)
            r[j] = __fadd_rn(r[j], __fmul_rn(z[i + j], z[i + j]));
    }
    float t01 = __fadd_rn(r[0], r[1]), t23 = __fadd_rn(r[2], r[3]);
    float t45 = __fadd_rn(r[4], r[5]), t67 = __fadd_rn(r[6], r[7]);
    return __fadd_rn(__fadd_rn(t01, t23), __fadd_rn(t45, t67));
}

// ---------------- Stage 1 (FUSED): z32 + zbf frags + A32 + thr ----------------
__global__ __launch_bounds__(256) void pre_quant_fused(const float* __restrict__ x,
                                                       const float* __restrict__ Wpre,
                                                       const float* __restrict__ bpre,
                                                       float* __restrict__ z32,
                                                       unsigned short* __restrict__ zbf,
                                                       float* __restrict__ A32,
                                                       float* __restrict__ thr) {
#pragma clang fp contract(off)
    __shared__ float xs[32][36];
    __shared__ float wt[32][260];   // [c][e]; aliased as zs[32][260] in epilogue
    int n0 = blockIdx.x * 32;
    int b = n0 >> 8, pix0 = n0 & 255;
    int t = threadIdx.x;
    int ep = t & 31, pg = t >> 5;

    f32x2 acc[4][4];
#pragma unroll
    for (int pi = 0; pi < 4; ++pi)
#pragma unroll
        for (int j = 0; j < 4; ++j) acc[pi][j] = (f32x2){0.f, 0.f};

    for (int c0 = 0; c0 < 256; c0 += 32) {
        __syncthreads();
        {   int cc = t >> 3, pp = (t & 7) * 4;
            *(float4*)&xs[cc][pp] =
                *(const float4*)&x[(size_t)b * 65536 + (size_t)(c0 + cc) * 256 + pix0 + pp];
        }
        {   const float* wr = Wpre + (size_t)t * 256 + c0;
#pragma unroll
            for (int i = 0; i < 32; i += 4) {
                float4 v = *(const float4*)&wr[i];
                wt[i + 0][t] = v.x; wt[i + 1][t] = v.y;
                wt[i + 2][t] = v.z; wt[i + 3][t] = v.w;
            }
        }
        __syncthreads();
#pragma unroll 8
        for (int cc = 0; cc < 32; ++cc) {
            float4 xv = *(const float4*)&xs[cc][pg * 4];
            float xa[4] = {xv.x, xv.y, xv.z, xv.w};
            f32x2 wv[4];
#pragma unroll
            for (int j = 0; j < 4; ++j) wv[j] = *(const f32x2*)&wt[cc][2 * ep + 64 * j];
#pragma unroll
            for (int pi = 0; pi < 4; ++pi) {
                f32x2 xsp = {xa[pi], xa[pi]};
#pragma unroll
                for (int j = 0; j < 4; ++j) {
                    f32x2 m = wv[j] * xsp;       // pk_mul (rounded)
                    acc[pi][j] = acc[pi][j] + m;  // pk_add (rounded) — contract off
                }
            }
        }
    }
    __syncthreads();   // all wt reads done before aliasing writes
    float* zs = &wt[0][0];   // [32][260]
    f32x2 b2[4];
#pragma unroll
    for (int j = 0; j < 4; ++j) b2[j] = *(const f32x2*)&bpre[2 * ep + 64 * j];
#pragma unroll
    for (int pi = 0; pi < 4; ++pi) {
        int row = pg * 4 + pi;
#pragma unroll
        for (int j = 0; j < 4; ++j) {
            f32x2 o = acc[pi][j] + b2[j];
            *(f32x2*)&z32[(size_t)(n0 + row) * 256 + 2 * ep + 64 * j] = o;
            *(f32x2*)&zs[row * 260 + 2 * ep + 64 * j] = o;
        }
    }
    __syncthreads();
#pragma unroll
    for (int q = 0; q < 4; ++q) {
        int uid = q * 256 + t;
        int l = uid & 63, ks = (uid >> 6) & 7, tile = uid >> 9;
        int rowl = tile * 16 + (l & 15), colb = ks * 32 + (l >> 4) * 8;
        const float* s = &zs[rowl * 260 + colb];
        float4 a = *(const float4*)s, bb = *(const float4*)(s + 4);
        u16x8 o;
        o[0] = f2bf(a.x); o[1] = f2bf(a.y); o[2] = f2bf(a.z); o[3] = f2bf(a.w);
        o[4] = f2bf(bb.x); o[5] = f2bf(bb.y); o[6] = f2bf(bb.z); o[7] = f2bf(bb.w);
        *((u16x8*)zbf + (((size_t)((n0 >> 4) + tile) * 8 + ks) * 64 + l)) = o;
    }
    if (t < 32) {
        float a = __fadd_rn(np_sqpair128(&zs[t * 260]), np_sqpair128(&zs[t * 260 + 128]));
        A32[n0 + t] = a;
        thr[n0 + t] = 2.75f * sqrtf(a) * 7.0466e-5f - 1e-6f;
    }
}

// ---------------- cb norms (np pairwise semantics) ----------------
__global__ __launch_bounds__(256) void cb_norms(const float* __restrict__ cb,
                                                float* __restrict__ C32) {
    int v = blockIdx.x * 256 + threadIdx.x;
    const float* r = cb + (size_t)v * 256;
    C32[v] = __fadd_rn(np_sqpair128(r), np_sqpair128(r + 128));
}

// ---------------- fragment-layout bf16 builder (codebook) ----------------
__global__ __launch_bounds__(256) void build_frag(const float* __restrict__ src,
                                                  unsigned short* __restrict__ dst) {
    int gid = blockIdx.x * 256 + threadIdx.x;
    int l = gid & 63, ks = (gid >> 6) & 7, tile = gid >> 9;
    int row = tile * 16 + (l & 15);
    int k = ks * 32 + (l >> 4) * 8;
    const float* s = src + (size_t)row * 256 + k;
    float4 a = *(const float4*)s, b = *(const float4*)(s + 4);
    u16x8 o;
    o[0] = f2bf(a.x); o[1] = f2bf(a.y); o[2] = f2bf(a.z); o[3] = f2bf(a.w);
    o[4] = f2bf(b.x); o[5] = f2bf(b.y); o[6] = f2bf(b.z); o[7] = f2bf(b.w);
    *((u16x8*)dst + gid) = o;
}

// ---------------- Stage 2: MFMA screen (r10 geometry + LDS-atomic append) ----------------
// r11 post-mortem: __launch_bounds__(512,4) capped regs at 128 < zf footprint ->
// scratch spill, FETCH 313MB, 366us. Revert to (512,2)/64KB phases (r10's 96us
// config); keep only the LDS-atomic append (fires on ~0.3% of lane-checks) in
// place of wave-wide ballot+mbcnt chains. Queue order differs; rerank min is
// order-independent -> tokens unchanged.
__global__ __launch_bounds__(512, 2) void screen(const unsigned short* __restrict__ zbf,
                                                 const unsigned short* __restrict__ cbf,
                                                 const float* __restrict__ C32,
                                                 const float* __restrict__ thr,
                                                 int* __restrict__ cnt,
                                                 int* __restrict__ cand) {
    __shared__ __align__(16) char lds[2][65536];
    __shared__ unsigned q[8][QCAP];   // 16 KiB per-wave candidate queues
    __shared__ int wq[8];
    int t = threadIdx.x, w = t >> 6, l = t & 63;
    int bid = blockIdx.x;
    int x = bid & 7, k = bid >> 3;
    int rowblk = (x & 3) * 8 + (k & 7);
    int vblk   = (x >> 2) * 4 + (k >> 3);
    int rb = rowblk * 512 + w * 64;

    const char* cbase = (const char*)cbf + (size_t)vblk * 524288;
    {   // issue phase-0 staging first so it overlaps the zf loads below
#pragma unroll
        for (int qq = 0; qq < 8; ++qq)
            gload_lds16(cbase + qq * 8192 + t * 16, &lds[0][0] + qq * 8192 + t * 16);
    }

    bf16x8 zf[4][8];
#pragma unroll
    for (int tt = 0; tt < 4; ++tt)
#pragma unroll
        for (int ks = 0; ks < 8; ++ks) {
            zf[tt][ks] = *((const bf16x8*)zbf + (((size_t)((rb >> 4) + tt) * 8 + ks) * 64 + l));
            asm volatile("" : "+a"(zf[tt][ks]));
        }

    int   rown[4];
    float thrv[4];
#pragma unroll
    for (int tt = 0; tt < 4; ++tt) {
        rown[tt] = rb + tt * 16 + (l & 15);
        thrv[tt] = thr[rown[tt]];
    }
    if (t < 8) wq[t] = 0;
    __syncthreads();

    for (int p = 0; p < 8; ++p) {
        int cur = p & 1;
        if (p < 7) {
            const char* src = cbase + (size_t)(p + 1) * 65536;
            char* dst = &lds[cur ^ 1][0];
#pragma unroll
            for (int qq = 0; qq < 8; ++qq)
                gload_lds16(src + qq * 8192 + t * 16, dst + qq * 8192 + t * 16);
        }
        const char* buf = &lds[cur][0];
#pragma unroll 2
        for (int vt = 0; vt < 8; ++vt) {
            f32x4 acc[4];
#pragma unroll
            for (int tt = 0; tt < 4; ++tt) acc[tt] = (f32x4){0.f, 0.f, 0.f, 0.f};
#pragma unroll
            for (int ks = 0; ks < 8; ++ks) {
                bf16x8 af = *(const bf16x8*)(buf + vt * 8192 + ks * 1024 + l * 16);
#pragma unroll
                for (int tt = 0; tt < 4; ++tt)
                    acc[tt] = __builtin_amdgcn_mfma_f32_16x16x32_bf16(af, zf[tt][ks], acc[tt], 0, 0, 0);
            }
            int v0 = vblk * 1024 + p * 128 + vt * 16 + (l >> 4) * 4;
            float4 c4 = *(const float4*)&C32[v0];
            float cv[4] = {c4.x, c4.y, c4.z, c4.w};
#pragma unroll
            for (int tt = 0; tt < 4; ++tt)
#pragma unroll
                for (int j = 0; j < 4; ++j) {
                    float s = __fmaf_rn(-0.5f, cv[j], acc[tt][j]);
                    if (s > thrv[tt]) {   // rare (~0.3% of lane-checks)
                        int slot = atomicAdd(&wq[w], 1);   // LDS atomic, wave-private
                        unsigned pk = ((unsigned)rown[tt] << 13) | (unsigned)(v0 + j);
                        if (slot < QCAP) q[w][slot] = pk;
                        else {   // astronomically rare overflow: direct append
                            int sl = atomicAdd(&cnt[rown[tt]], 1);
                            if (sl < 64) cand[(size_t)rown[tt] * 64 + sl] = v0 + j;
                        }
                    }
                }
        }
        __syncthreads();
    }

    // per-wave flush: queue -> global (atomic latency exposed once, not per fire)
    int nq = wq[w] < QCAP ? wq[w] : QCAP;
    for (int i = l; i < nq; i += 64) {
        unsigned pk = q[w][i];
        int row = pk >> 13, v = pk & 8191;
        int sl = atomicAdd(&cnt[row], 1);
        if (sl < 64) cand[(size_t)row * 64 + sl] = v;
    }
}

// ---------------- Stage 3: exact np-f32 re-rank v3 ([k][item] LDS, reg-prefetch) ----------------
// r11: rerank dropped out of top-5 (~70us). Unchanged.
__global__ __launch_bounds__(256, 3) void rerank(const float* __restrict__ z32,
                                                 const float* __restrict__ cb,
                                                 const float* __restrict__ A32,
                                                 const float* __restrict__ C32,
                                                 const int* __restrict__ cand,
                                                 const int* __restrict__ cnt,
                                                 int* __restrict__ tok_i,
                                                 float* __restrict__ tok_f) {
    __shared__ float    sbuf[32][265];   // [k][item], 33.9 KB
    __shared__ float    zs[8][264];      // z rows, 8.4 KB
    __shared__ unsigned sv[512];         // packed (row<<13)|v
    __shared__ int      sh[9];
    __shared__ float    dbuf[8][64];
    __shared__ int      vbuf[8][64];
    int t = threadIdx.x;
    int n0 = blockIdx.x * 8;

    if (t == 0) {
        int o = 0;
#pragma unroll
        for (int r = 0; r < 8; ++r) {
            sh[r] = o;
            int n = cnt[n0 + r]; if (n > 64) n = 64;
            o += n;
        }
        sh[8] = o;
    }
    {   // stage z rows (coalesced) + init result slots
        int r = t >> 5, e = (t & 31) * 8;
        const float* zr = &z32[(size_t)(n0 + r) * 256 + e];
        *(float4*)&zs[r][e]     = *(const float4*)zr;
        *(float4*)&zs[r][e + 4] = *(const float4*)(zr + 4);
        int sl = t & 31;
        dbuf[r][sl] = 3.4e38f;      dbuf[r][sl + 32] = 3.4e38f;
        vbuf[r][sl] = 0x7fffffff;   vbuf[r][sl + 32] = 0x7fffffff;
    }
    __syncthreads();
    int m = sh[8];

    for (int i = t; i < m; i += 256) {
        int r = 0;
#pragma unroll
        for (int j = 1; j < 8; ++j) r += (i >= sh[j]);
        unsigned v = (unsigned)cand[(size_t)(n0 + r) * 64 + (i - sh[r])];
        sv[i] = ((unsigned)r << 13) | v;
    }
    __syncthreads();

    for (int b0 = 0; b0 < m; b0 += 256) {
        int mb = m - b0; if (mb > 256) mb = 256;
        bool act = t < mb;
        unsigned pk = act ? sv[b0 + t] : 0;
        int myrow = pk >> 13, myv = pk & 8191;
        float s = 0.0f;

        float4 pf[8];
#pragma unroll
        for (int j = 0; j < 8; ++j) {
            int i = j * 32 + (t >> 3);
            if (i < mb) {
                unsigned vv = sv[b0 + i] & 8191u;
                pf[j] = *(const float4*)&cb[(size_t)vv * 256 + (t & 7) * 4];
            }
        }
        for (int c = 0; c < 8; ++c) {
            __syncthreads();   // prior chunk's sbuf reads complete
#pragma unroll
            for (int j = 0; j < 8; ++j) {
                int i = j * 32 + (t >> 3);
                if (i < mb) {
                    int kb = (t & 7) * 4;
                    sbuf[kb + 0][i] = pf[j].x; sbuf[kb + 1][i] = pf[j].y;
                    sbuf[kb + 2][i] = pf[j].z; sbuf[kb + 3][i] = pf[j].w;
                }
            }
            __syncthreads();
            if (c < 7) {   // issue next chunk's loads; latency hides under compute
#pragma unroll
                for (int j = 0; j < 8; ++j) {
                    int i = j * 32 + (t >> 3);
                    if (i < mb) {
                        unsigned vv = sv[b0 + i] & 8191u;
                        pf[j] = *(const float4*)&cb[(size_t)vv * 256 + (c + 1) * 32 + (t & 7) * 4];
                    }
                }
            }
            if (act) {
                const float* zz = &zs[myrow][c * 32];
#pragma unroll
                for (int k = 0; k < 32; ++k)
                    s = __fmaf_rn(sbuf[k][t], zz[k], s);   // ascending k (r2 chain)
            }
        }
        if (act) {
            float d = __fadd_rn(__fsub_rn(A32[n0 + myrow], __fmul_rn(2.0f, s)), C32[myv]);
            int slot = (b0 + t) - sh[myrow];
            dbuf[myrow][slot] = d;
            vbuf[myrow][slot] = myv;
        }
    }
    __syncthreads();
    {   // per-row argmin: 32 threads per row
        int r = t >> 5, l5 = t & 31;
        float d1 = dbuf[r][l5], d2 = dbuf[r][l5 + 32];
        int   v1 = vbuf[r][l5], v2 = vbuf[r][l5 + 32];
        if (d2 < d1 || (d2 == d1 && v2 < v1)) { d1 = d2; v1 = v2; }
#pragma unroll
        for (int off = 16; off > 0; off >>= 1) {
            float dd = __shfl_xor(d1, off, 32);
            int   vv = __shfl_xor(v1, off, 32);
            if (dd < d1 || (dd == d1 && vv < v1)) { d1 = dd; v1 = vv; }
        }
        if (l5 == 0) { tok_i[n0 + r] = v1; tok_f[n0 + r] = (float)v1; }
    }
}

// ---------------- Stage 4: rec = codebook[tok] @ W_post^T + b_post ----------------
__global__ __launch_bounds__(256) void post_quant(const float* __restrict__ cb,
                                                  const float* __restrict__ Wpost,
                                                  const float* __restrict__ bpost,
                                                  const int* __restrict__ tok,
                                                  float* __restrict__ rec) {
    __shared__ float zq[256][36];   // [e][pix]
    __shared__ float wt[32][260];   // [e-chunk][cout]
    int n0 = blockIdx.x * 32;
    int b = n0 >> 8, pix0 = n0 & 255;
    int t = threadIdx.x;
    int ep = t & 31, pg = t >> 5;

    {   int pix = t & 31, eg = t >> 5;
        int tv = tok[n0 + pix];
        const float* cr = cb + (size_t)tv * 256 + eg * 32;
#pragma unroll
        for (int i = 0; i < 32; ++i)
            zq[eg * 32 + i][pix] = cr[i];
    }

    f32x2 acc[8][2];
#pragma unroll
    for (int s = 0; s < 8; ++s) { acc[s][0] = (f32x2){0.f, 0.f}; acc[s][1] = (f32x2){0.f, 0.f}; }

    for (int e0 = 0; e0 < 256; e0 += 32) {
        __syncthreads();
        const float* wr = Wpost + (size_t)t * 256 + e0;
#pragma unroll
        for (int i = 0; i < 32; i += 4) {
            float4 v = *(const float4*)&wr[i];
            wt[i + 0][t] = v.x; wt[i + 1][t] = v.y;
            wt[i + 2][t] = v.z; wt[i + 3][t] = v.w;
        }
        __syncthreads();
#pragma unroll 8
        for (int ee = 0; ee < 32; ++ee) {
            float4 zv = *(const float4*)&zq[e0 + ee][pg * 4];
            f32x2 zp0 = {zv.x, zv.y}, zp1 = {zv.z, zv.w};
#pragma unroll
            for (int J = 0; J < 4; ++J) {
                f32x2 wv = *(const f32x2*)&wt[ee][2 * ep + 64 * J];
                f32x2 w0 = {wv[0], wv[0]}, w1 = {wv[1], wv[1]};
                acc[2 * J + 0][0] = w0 * zp0 + acc[2 * J + 0][0];
                acc[2 * J + 0][1] = w0 * zp1 + acc[2 * J + 0][1];
                acc[2 * J + 1][0] = w1 * zp0 + acc[2 * J + 1][0];
                acc[2 * J + 1][1] = w1 * zp1 + acc[2 * J + 1][1];
            }
        }
    }
#pragma unroll
    for (int J = 0; J < 4; ++J)
#pragma unroll
        for (int c01 = 0; c01 < 2; ++c01) {
            int cout = 2 * ep + 64 * J + c01;
            float bv = bpost[cout];
            f32x2 bs = {bv, bv};
            f32x2 o0 = acc[2 * J + c01][0] + bs, o1 = acc[2 * J + c01][1] + bs;
            float4 ov = {o0[0], o0[1], o1[0], o1[1]};
            *(float4*)&rec[(size_t)b * 65536 + (size_t)cout * 256 + pix0 + pg * 4] = ov;
        }
}

// ---------------- Launch ----------------
extern "C" void kernel_launch(void* const* d_in, const int* in_sizes, int n_in,
                              void* d_out, int out_size, void* d_ws, size_t ws_size,
                              hipStream_t stream) {
    const float* x     = (const float*)d_in[0];
    const float* Wpre  = (const float*)d_in[1];
    const float* bpre  = (const float*)d_in[2];
    const float* cb    = (const float*)d_in[3];
    const float* Wpost = (const float*)d_in[4];
    const float* bpost = (const float*)d_in[5];

    float* out   = (float*)d_out;
    float* rec   = out;
    float* tok_f = out + 4194304;
    float* z32   = rec;   // z lives in rec region until post_quant overwrites it

    char* ws = (char*)d_ws;
    float*          A32   = (float*)(ws + 0);         // 64 KiB
    float*          C32   = (float*)(ws + 65536);     // 32 KiB
    int*            tok_i = (int*)(ws + 98304);       // 64 KiB
    float*          thr   = (float*)(ws + 163840);    // 64 KiB
    int*            cnt   = (int*)(ws + 229376);      // 64 KiB
    int*            cand  = (int*)(ws + 294912);      // 4 MiB
    unsigned short* zbf   = (unsigned short*)(ws + 4489216);   // 8 MiB
    unsigned short* cbf   = (unsigned short*)(ws + 12877824);  // 4 MiB

    pre_quant_fused<<<NPIX / 32, 256, 0, stream>>>(x, Wpre, bpre, z32, zbf, A32, thr);
    cb_norms<<<VDIM / 256, 256, 0, stream>>>(cb, C32);
    build_frag<<<(VDIM / 16) * 8 * 64 / 256, 256, 0, stream>>>(cb, cbf);
    hipMemsetAsync(cnt, 0, NPIX * sizeof(int), stream);
    screen<<<256, 512, 0, stream>>>(zbf, cbf, C32, thr, cnt, cand);
    rerank<<<NPIX / 8, 256, 0, stream>>>(z32, cb, A32, C32, cand, cnt, tok_i, tok_f);
    post_quant<<<NPIX / 32, 256, 0, stream>>>(cb, Wpost, bpost, tok_i, rec);
}

// Round 13
// 268.423 us; speedup vs baseline: 2.0123x; 1.0232x over previous
//
#include <hip/hip_runtime.h>
#include <cstdint>
#include <cstddef>

#define EDIM 256
#define VDIM 8192
#define NPIX 16384
#define QCAP 512

typedef __attribute__((ext_vector_type(8))) short          bf16x8;
typedef __attribute__((ext_vector_type(8))) unsigned short u16x8;
typedef __attribute__((ext_vector_type(4))) float          f32x4;
typedef __attribute__((ext_vector_type(2))) float          f32x2;

// RNE float->bf16
__device__ __forceinline__ unsigned short f2bf(float x) {
    unsigned int u = __float_as_uint(x);
    return (unsigned short)((u + 0x7fffu + ((u >> 16) & 1u)) >> 16);
}

// ---------- numpy pairwise sum-of-squares (exact semantics, verified r2) ----------
__device__ __forceinline__ float np_sqpair128(const float* __restrict__ z) {
    float r[8];
#pragma unroll
    for (int j = 0; j < 8; ++j) r[j] = __fmul_rn(z[j], z[j]);
    for (int i = 8; i < 128; i += 8) {
#pragma unroll
        for (int j = 0; j < 8; ++j)
            r[j] = __fadd_rn(r[j], __fmul_rn(z[i + j], z[i + j]));
    }
    float t01 = __fadd_rn(r[0], r[1]), t23 = __fadd_rn(r[2], r[3]);
    float t45 = __fadd_rn(r[4], r[5]), t67 = __fadd_rn(r[6], r[7]);
    return __fadd_rn(__fadd_rn(t01, t23), __fadd_rn(t45, t67));
}

// ---------------- Stage 1 (FUSED): z32 + zbf frags + A32 + thr ----------------
__global__ __launch_bounds__(256) void pre_quant_fused(const float* __restrict__ x,
                                                       const float* __restrict__ Wpre,
                                                       const float* __restrict__ bpre,
                                                       float* __restrict__ z32,
                                                       unsigned short* __restrict__ zbf,
                                                       float* __restrict__ A32,
                                                       float* __restrict__ thr) {
#pragma clang fp contract(off)
    __shared__ float xs[32][36];
    __shared__ float wt[32][260];   // [c][e]; aliased as zs[32][260] in epilogue
    int n0 = blockIdx.x * 32;
    int b = n0 >> 8, pix0 = n0 & 255;
    int t = threadIdx.x;
    int ep = t & 31, pg = t >> 5;

    f32x2 acc[4][4];
#pragma unroll
    for (int pi = 0; pi < 4; ++pi)
#pragma unroll
        for (int j = 0; j < 4; ++j) acc[pi][j] = (f32x2){0.f, 0.f};

    for (int c0 = 0; c0 < 256; c0 += 32) {
        __syncthreads();
        {   int cc = t >> 3, pp = (t & 7) * 4;
            *(float4*)&xs[cc][pp] =
                *(const float4*)&x[(size_t)b * 65536 + (size_t)(c0 + cc) * 256 + pix0 + pp];
        }
        {   const float* wr = Wpre + (size_t)t * 256 + c0;
#pragma unroll
            for (int i = 0; i < 32; i += 4) {
                float4 v = *(const float4*)&wr[i];
                wt[i + 0][t] = v.x; wt[i + 1][t] = v.y;
                wt[i + 2][t] = v.z; wt[i + 3][t] = v.w;
            }
        }
        __syncthreads();
#pragma unroll 8
        for (int cc = 0; cc < 32; ++cc) {
            float4 xv = *(const float4*)&xs[cc][pg * 4];
            float xa[4] = {xv.x, xv.y, xv.z, xv.w};
            f32x2 wv[4];
#pragma unroll
            for (int j = 0; j < 4; ++j) wv[j] = *(const f32x2*)&wt[cc][2 * ep + 64 * j];
#pragma unroll
            for (int pi = 0; pi < 4; ++pi) {
                f32x2 xsp = {xa[pi], xa[pi]};
#pragma unroll
                for (int j = 0; j < 4; ++j) {
                    f32x2 m = wv[j] * xsp;       // pk_mul (rounded)
                    acc[pi][j] = acc[pi][j] + m;  // pk_add (rounded) — contract off
                }
            }
        }
    }
    __syncthreads();   // all wt reads done before aliasing writes
    float* zs = &wt[0][0];   // [32][260]
    f32x2 b2[4];
#pragma unroll
    for (int j = 0; j < 4; ++j) b2[j] = *(const f32x2*)&bpre[2 * ep + 64 * j];
#pragma unroll
    for (int pi = 0; pi < 4; ++pi) {
        int row = pg * 4 + pi;
#pragma unroll
        for (int j = 0; j < 4; ++j) {
            f32x2 o = acc[pi][j] + b2[j];
            *(f32x2*)&z32[(size_t)(n0 + row) * 256 + 2 * ep + 64 * j] = o;
            *(f32x2*)&zs[row * 260 + 2 * ep + 64 * j] = o;
        }
    }
    __syncthreads();
#pragma unroll
    for (int q = 0; q < 4; ++q) {
        int uid = q * 256 + t;
        int l = uid & 63, ks = (uid >> 6) & 7, tile = uid >> 9;
        int rowl = tile * 16 + (l & 15), colb = ks * 32 + (l >> 4) * 8;
        const float* s = &zs[rowl * 260 + colb];
        float4 a = *(const float4*)s, bb = *(const float4*)(s + 4);
        u16x8 o;
        o[0] = f2bf(a.x); o[1] = f2bf(a.y); o[2] = f2bf(a.z); o[3] = f2bf(a.w);
        o[4] = f2bf(bb.x); o[5] = f2bf(bb.y); o[6] = f2bf(bb.z); o[7] = f2bf(bb.w);
        *((u16x8*)zbf + (((size_t)((n0 >> 4) + tile) * 8 + ks) * 64 + l)) = o;
    }
    if (t < 32) {
        float a = __fadd_rn(np_sqpair128(&zs[t * 260]), np_sqpair128(&zs[t * 260 + 128]));
        A32[n0 + t] = a;
        thr[n0 + t] = 2.75f * sqrtf(a) * 7.0466e-5f - 1e-6f;
    }
}

// ---------------- cb norms (np pairwise semantics) ----------------
__global__ __launch_bounds__(256) void cb_norms(const float* __restrict__ cb,
                                                float* __restrict__ C32) {
    int v = blockIdx.x * 256 + threadIdx.x;
    const float* r = cb + (size_t)v * 256;
    C32[v] = __fadd_rn(np_sqpair128(r), np_sqpair128(r + 128));
}

// ---------------- fragment-layout bf16 builder (codebook) ----------------
__global__ __launch_bounds__(256) void build_frag(const float* __restrict__ src,
                                                  unsigned short* __restrict__ dst) {
    int gid = blockIdx.x * 256 + threadIdx.x;
    int l = gid & 63, ks = (gid >> 6) & 7, tile = gid >> 9;
    int row = tile * 16 + (l & 15);
    int k = ks * 32 + (l >> 4) * 8;
    const float* s = src + (size_t)row * 256 + k;
    float4 a = *(const float4*)s, b = *(const float4*)(s + 4);
    u16x8 o;
    o[0] = f2bf(a.x); o[1] = f2bf(a.y); o[2] = f2bf(a.z); o[3] = f2bf(a.w);
    o[4] = f2bf(b.x); o[5] = f2bf(b.y); o[6] = f2bf(b.z); o[7] = f2bf(b.w);
    *((u16x8*)dst + gid) = o;
}

// ---------------- Stage 2: MFMA screen v8 (LDS-FREE, barrier-free main loop) ----------------
// r12 post-mortem: zf regs (~230) pin us at 8 waves/CU -> the per-phase syncthreads
// (vmcnt(0) drain of 64KB staging) has no co-resident block to hide behind: wall
// 101us vs ~26us of real work. v8: read A-fragments DIRECTLY from L2-resident cbf
// (512KB/XCD slice) into a 2-tile register double-buffer (even/odd unrolled, no
// moves, no dynamic indexing). Zero syncthreads in the loop; 8 loads hidden under
// 32 MFMA + 2-wave/SIMD overlap. LDS = 16KB queues only.
#define COMPUTE_TILE(AF, TI)                                                        \
    do {                                                                            \
        f32x4 a0 = {0.f,0.f,0.f,0.f}, a1 = {0.f,0.f,0.f,0.f};                       \
        f32x4 a2 = {0.f,0.f,0.f,0.f}, a3 = {0.f,0.f,0.f,0.f};                       \
        _Pragma("unroll")                                                           \
        for (int ks = 0; ks < 8; ++ks) {                                            \
            a0 = __builtin_amdgcn_mfma_f32_16x16x32_bf16(AF[ks], zf[0][ks], a0,0,0,0); \
            a1 = __builtin_amdgcn_mfma_f32_16x16x32_bf16(AF[ks], zf[1][ks], a1,0,0,0); \
            a2 = __builtin_amdgcn_mfma_f32_16x16x32_bf16(AF[ks], zf[2][ks], a2,0,0,0); \
            a3 = __builtin_amdgcn_mfma_f32_16x16x32_bf16(AF[ks], zf[3][ks], a3,0,0,0); \
        }                                                                           \
        int v0 = vblk * 1024 + (TI) * 16 + (l >> 4) * 4;                            \
        float4 c4 = *(const float4*)&C32[v0];                                       \
        float cv[4] = {c4.x, c4.y, c4.z, c4.w};                                     \
        f32x4 aa[4] = {a0, a1, a2, a3};                                             \
        _Pragma("unroll")                                                           \
        for (int tt = 0; tt < 4; ++tt)                                              \
            _Pragma("unroll")                                                       \
            for (int j = 0; j < 4; ++j) {                                           \
                float s = __fmaf_rn(-0.5f, cv[j], aa[tt][j]);                       \
                if (s > thrv[tt]) {                                                 \
                    int slot = atomicAdd(&wq[w], 1);                                \
                    unsigned pk = ((unsigned)rown[tt] << 13) | (unsigned)(v0 + j);  \
                    if (slot < QCAP) q[w][slot] = pk;                               \
                    else {                                                          \
                        int sl = atomicAdd(&cnt[rown[tt]], 1);                      \
                        if (sl < 64) cand[(size_t)rown[tt] * 64 + sl] = v0 + j;     \
                    }                                                               \
                }                                                                   \
            }                                                                       \
    } while (0)

__global__ __launch_bounds__(512) void screen(const unsigned short* __restrict__ zbf,
                                              const unsigned short* __restrict__ cbf,
                                              const float* __restrict__ C32,
                                              const float* __restrict__ thr,
                                              int* __restrict__ cnt,
                                              int* __restrict__ cand) {
    __shared__ unsigned q[8][QCAP];   // 16 KiB per-wave candidate queues
    __shared__ int wq[8];
    int t = threadIdx.x, w = t >> 6, l = t & 63;
    int bid = blockIdx.x;
    int x = bid & 7, k = bid >> 3;
    int rowblk = (x & 3) * 8 + (k & 7);
    int vblk   = (x >> 2) * 4 + (k >> 3);
    int rb = rowblk * 512 + w * 64;

    bf16x8 zf[4][8];
#pragma unroll
    for (int tt = 0; tt < 4; ++tt)
#pragma unroll
        for (int ks = 0; ks < 8; ++ks) {
            zf[tt][ks] = *((const bf16x8*)zbf + (((size_t)((rb >> 4) + tt) * 8 + ks) * 64 + l));
            asm volatile("" : "+a"(zf[tt][ks]));
        }

    int   rown[4];
    float thrv[4];
#pragma unroll
    for (int tt = 0; tt < 4; ++tt) {
        rown[tt] = rb + tt * 16 + (l & 15);
        thrv[tt] = thr[rown[tt]];
    }
    if (t < 8) wq[t] = 0;
    __syncthreads();   // queues ready (only barrier before flush)

    const bf16x8* cb8 = (const bf16x8*)cbf;
    size_t tb = (size_t)(vblk * 64) * 512;   // frag-elems: tile i at tb + i*512 + ks*64 + l

    bf16x8 afA[8], afB[8];
#pragma unroll
    for (int ks = 0; ks < 8; ++ks)
        afA[ks] = cb8[tb + ks * 64 + l];

#pragma unroll 1
    for (int i = 0; i < 64; i += 2) {
        size_t nb = tb + (size_t)(i + 1) * 512;
#pragma unroll
        for (int ks = 0; ks < 8; ++ks)
            afB[ks] = cb8[nb + ks * 64 + l];          // prefetch odd tile
        COMPUTE_TILE(afA, i);                          // compute even tile
        if (i < 62) {
            size_t nb2 = tb + (size_t)(i + 2) * 512;
#pragma unroll
            for (int ks = 0; ks < 8; ++ks)
                afA[ks] = cb8[nb2 + ks * 64 + l];      // prefetch next even tile
        }
        COMPUTE_TILE(afB, i + 1);                      // compute odd tile
    }
    __syncthreads();

    // per-wave flush: queue -> global (atomic latency exposed once, not per fire)
    int nq = wq[w] < QCAP ? wq[w] : QCAP;
    for (int i = l; i < nq; i += 64) {
        unsigned pk = q[w][i];
        int row = pk >> 13, v = pk & 8191;
        int sl = atomicAdd(&cnt[row], 1);
        if (sl < 64) cand[(size_t)row * 64 + sl] = v;
    }
}

// ---------------- Stage 3: exact np-f32 re-rank v3 ([k][item] LDS, reg-prefetch) ----------------
__global__ __launch_bounds__(256, 3) void rerank(const float* __restrict__ z32,
                                                 const float* __restrict__ cb,
                                                 const float* __restrict__ A32,
                                                 const float* __restrict__ C32,
                                                 const int* __restrict__ cand,
                                                 const int* __restrict__ cnt,
                                                 int* __restrict__ tok_i,
                                                 float* __restrict__ tok_f) {
    __shared__ float    sbuf[32][265];   // [k][item], 33.9 KB
    __shared__ float    zs[8][264];      // z rows, 8.4 KB
    __shared__ unsigned sv[512];         // packed (row<<13)|v
    __shared__ int      sh[9];
    __shared__ float    dbuf[8][64];
    __shared__ int      vbuf[8][64];
    int t = threadIdx.x;
    int n0 = blockIdx.x * 8;

    if (t == 0) {
        int o = 0;
#pragma unroll
        for (int r = 0; r < 8; ++r) {
            sh[r] = o;
            int n = cnt[n0 + r]; if (n > 64) n = 64;
            o += n;
        }
        sh[8] = o;
    }
    {   // stage z rows (coalesced) + init result slots
        int r = t >> 5, e = (t & 31) * 8;
        const float* zr = &z32[(size_t)(n0 + r) * 256 + e];
        *(float4*)&zs[r][e]     = *(const float4*)zr;
        *(float4*)&zs[r][e + 4] = *(const float4*)(zr + 4);
        int sl = t & 31;
        dbuf[r][sl] = 3.4e38f;      dbuf[r][sl + 32] = 3.4e38f;
        vbuf[r][sl] = 0x7fffffff;   vbuf[r][sl + 32] = 0x7fffffff;
    }
    __syncthreads();
    int m = sh[8];

    for (int i = t; i < m; i += 256) {
        int r = 0;
#pragma unroll
        for (int j = 1; j < 8; ++j) r += (i >= sh[j]);
        unsigned v = (unsigned)cand[(size_t)(n0 + r) * 64 + (i - sh[r])];
        sv[i] = ((unsigned)r << 13) | v;
    }
    __syncthreads();

    for (int b0 = 0; b0 < m; b0 += 256) {
        int mb = m - b0; if (mb > 256) mb = 256;
        bool act = t < mb;
        unsigned pk = act ? sv[b0 + t] : 0;
        int myrow = pk >> 13, myv = pk & 8191;
        float s = 0.0f;

        float4 pf[8];
#pragma unroll
        for (int j = 0; j < 8; ++j) {
            int i = j * 32 + (t >> 3);
            if (i < mb) {
                unsigned vv = sv[b0 + i] & 8191u;
                pf[j] = *(const float4*)&cb[(size_t)vv * 256 + (t & 7) * 4];
            }
        }
        for (int c = 0; c < 8; ++c) {
            __syncthreads();   // prior chunk's sbuf reads complete
#pragma unroll
            for (int j = 0; j < 8; ++j) {
                int i = j * 32 + (t >> 3);
                if (i < mb) {
                    int kb = (t & 7) * 4;
                    sbuf[kb + 0][i] = pf[j].x; sbuf[kb + 1][i] = pf[j].y;
                    sbuf[kb + 2][i] = pf[j].z; sbuf[kb + 3][i] = pf[j].w;
                }
            }
            __syncthreads();
            if (c < 7) {   // issue next chunk's loads; latency hides under compute
#pragma unroll
                for (int j = 0; j < 8; ++j) {
                    int i = j * 32 + (t >> 3);
                    if (i < mb) {
                        unsigned vv = sv[b0 + i] & 8191u;
                        pf[j] = *(const float4*)&cb[(size_t)vv * 256 + (c + 1) * 32 + (t & 7) * 4];
                    }
                }
            }
            if (act) {
                const float* zz = &zs[myrow][c * 32];
#pragma unroll
                for (int k = 0; k < 32; ++k)
                    s = __fmaf_rn(sbuf[k][t], zz[k], s);   // ascending k (r2 chain)
            }
        }
        if (act) {
            float d = __fadd_rn(__fsub_rn(A32[n0 + myrow], __fmul_rn(2.0f, s)), C32[myv]);
            int slot = (b0 + t) - sh[myrow];
            dbuf[myrow][slot] = d;
            vbuf[myrow][slot] = myv;
        }
    }
    __syncthreads();
    {   // per-row argmin: 32 threads per row
        int r = t >> 5, l5 = t & 31;
        float d1 = dbuf[r][l5], d2 = dbuf[r][l5 + 32];
        int   v1 = vbuf[r][l5], v2 = vbuf[r][l5 + 32];
        if (d2 < d1 || (d2 == d1 && v2 < v1)) { d1 = d2; v1 = v2; }
#pragma unroll
        for (int off = 16; off > 0; off >>= 1) {
            float dd = __shfl_xor(d1, off, 32);
            int   vv = __shfl_xor(v1, off, 32);
            if (dd < d1 || (dd == d1 && vv < v1)) { d1 = dd; v1 = vv; }
        }
        if (l5 == 0) { tok_i[n0 + r] = v1; tok_f[n0 + r] = (float)v1; }
    }
}

// ---------------- Stage 4: rec = codebook[tok] @ W_post^T + b_post ----------------
__global__ __launch_bounds__(256) void post_quant(const float* __restrict__ cb,
                                                  const float* __restrict__ Wpost,
                                                  const float* __restrict__ bpost,
                                                  const int* __restrict__ tok,
                                                  float* __restrict__ rec) {
    __shared__ float zq[256][36];   // [e][pix]
    __shared__ float wt[32][260];   // [e-chunk][cout]
    int n0 = blockIdx.x * 32;
    int b = n0 >> 8, pix0 = n0 & 255;
    int t = threadIdx.x;
    int ep = t & 31, pg = t >> 5;

    {   int pix = t & 31, eg = t >> 5;
        int tv = tok[n0 + pix];
        const float* cr = cb + (size_t)tv * 256 + eg * 32;
#pragma unroll
        for (int i = 0; i < 32; ++i)
            zq[eg * 32 + i][pix] = cr[i];
    }

    f32x2 acc[8][2];
#pragma unroll
    for (int s = 0; s < 8; ++s) { acc[s][0] = (f32x2){0.f, 0.f}; acc[s][1] = (f32x2){0.f, 0.f}; }

    for (int e0 = 0; e0 < 256; e0 += 32) {
        __syncthreads();
        const float* wr = Wpost + (size_t)t * 256 + e0;
#pragma unroll
        for (int i = 0; i < 32; i += 4) {
            float4 v = *(const float4*)&wr[i];
            wt[i + 0][t] = v.x; wt[i + 1][t] = v.y;
            wt[i + 2][t] = v.z; wt[i + 3][t] = v.w;
        }
        __syncthreads();
#pragma unroll 8
        for (int ee = 0; ee < 32; ++ee) {
            float4 zv = *(const float4*)&zq[e0 + ee][pg * 4];
            f32x2 zp0 = {zv.x, zv.y}, zp1 = {zv.z, zv.w};
#pragma unroll
            for (int J = 0; J < 4; ++J) {
                f32x2 wv = *(const f32x2*)&wt[ee][2 * ep + 64 * J];
                f32x2 w0 = {wv[0], wv[0]}, w1 = {wv[1], wv[1]};
                acc[2 * J + 0][0] = w0 * zp0 + acc[2 * J + 0][0];
                acc[2 * J + 0][1] = w0 * zp1 + acc[2 * J + 0][1];
                acc[2 * J + 1][0] = w1 * zp0 + acc[2 * J + 1][0];
                acc[2 * J + 1][1] = w1 * zp1 + acc[2 * J + 1][1];
            }
        }
    }
#pragma unroll
    for (int J = 0; J < 4; ++J)
#pragma unroll
        for (int c01 = 0; c01 < 2; ++c01) {
            int cout = 2 * ep + 64 * J + c01;
            float bv = bpost[cout];
            f32x2 bs = {bv, bv};
            f32x2 o0 = acc[2 * J + c01][0] + bs, o1 = acc[2 * J + c01][1] + bs;
            float4 ov = {o0[0], o0[1], o1[0], o1[1]};
            *(float4*)&rec[(size_t)b * 65536 + (size_t)cout * 256 + pix0 + pg * 4] = ov;
        }
}

// ---------------- Launch ----------------
extern "C" void kernel_launch(void* const* d_in, const int* in_sizes, int n_in,
                              void* d_out, int out_size, void* d_ws, size_t ws_size,
                              hipStream_t stream) {
    const float* x     = (const float*)d_in[0];
    const float* Wpre  = (const float*)d_in[1];
    const float* bpre  = (const float*)d_in[2];
    const float* cb    = (const float*)d_in[3];
    const float* Wpost = (const float*)d_in[4];
    const float* bpost = (const float*)d_in[5];

    float* out   = (float*)d_out;
    float* rec   = out;
    float* tok_f = out + 4194304;
    float* z32   = rec;   // z lives in rec region until post_quant overwrites it

    char* ws = (char*)d_ws;
    float*          A32   = (float*)(ws + 0);         // 64 KiB
    float*          C32   = (float*)(ws + 65536);     // 32 KiB
    int*            tok_i = (int*)(ws + 98304);       // 64 KiB
    float*          thr   = (float*)(ws + 163840);    // 64 KiB
    int*            cnt   = (int*)(ws + 229376);      // 64 KiB
    int*            cand  = (int*)(ws + 294912);      // 4 MiB
    unsigned short* zbf   = (unsigned short*)(ws + 4489216);   // 8 MiB
    unsigned short* cbf   = (unsigned short*)(ws + 12877824);  // 4 MiB

    pre_quant_fused<<<NPIX / 32, 256, 0, stream>>>(x, Wpre, bpre, z32, zbf, A32, thr);
    cb_norms<<<VDIM / 256, 256, 0, stream>>>(cb, C32);
    build_frag<<<(VDIM / 16) * 8 * 64 / 256, 256, 0, stream>>>(cb, cbf);
    hipMemsetAsync(cnt, 0, NPIX * sizeof(int), stream);
    screen<<<256, 512, 0, stream>>>(zbf, cbf, C32, thr, cnt, cand);
    rerank<<<NPIX / 8, 256, 0, stream>>>(z32, cb, A32, C32, cand, cnt, tok_i, tok_f);
    post_quant<<<NPIX / 32, 256, 0, stream>>>(cb, Wpost, bpost, tok_i, rec);
}

// Round 14
// 265.109 us; speedup vs baseline: 2.0374x; 1.0125x over previous
//
#include <hip/hip_runtime.h>
#include <cstdint>
#include <cstddef>

#define EDIM 256
#define VDIM 8192
#define NPIX 16384
#define QCAP 512

typedef __attribute__((ext_vector_type(8))) short          bf16x8;
typedef __attribute__((ext_vector_type(8))) unsigned short u16x8;
typedef __attribute__((ext_vector_type(4))) float          f32x4;
typedef __attribute__((ext_vector_type(2))) float          f32x2;

// RNE float->bf16
__device__ __forceinline__ unsigned short f2bf(float x) {
    unsigned int u = __float_as_uint(x);
    return (unsigned short)((u + 0x7fffu + ((u >> 16) & 1u)) >> 16);
}

// ---------- numpy pairwise sum-of-squares (exact semantics, verified r2) ----------
__device__ __forceinline__ float np_sqpair128(const float* __restrict__ z) {
    float r[8];
#pragma unroll
    for (int j = 0; j < 8; ++j) r[j] = __fmul_rn(z[j], z[j]);
    for (int i = 8; i < 128; i += 8) {
#pragma unroll
        for (int j = 0; j < 8; ++j)
            r[j] = __fadd_rn(r[j], __fmul_rn(z[i + j], z[i + j]));
    }
    float t01 = __fadd_rn(r[0], r[1]), t23 = __fadd_rn(r[2], r[3]);
    float t45 = __fadd_rn(r[4], r[5]), t67 = __fadd_rn(r[6], r[7]);
    return __fadd_rn(__fadd_rn(t01, t23), __fadd_rn(t45, t67));
}

// ---------------- Stage 1 (FUSED): z32 + zbf frags + A32 + thr ----------------
__global__ __launch_bounds__(256) void pre_quant_fused(const float* __restrict__ x,
                                                       const float* __restrict__ Wpre,
                                                       const float* __restrict__ bpre,
                                                       float* __restrict__ z32,
                                                       unsigned short* __restrict__ zbf,
                                                       float* __restrict__ A32,
                                                       float* __restrict__ thr) {
#pragma clang fp contract(off)
    __shared__ float xs[32][36];
    __shared__ float wt[32][260];   // [c][e]; aliased as zs[32][260] in epilogue
    int n0 = blockIdx.x * 32;
    int b = n0 >> 8, pix0 = n0 & 255;
    int t = threadIdx.x;
    int ep = t & 31, pg = t >> 5;

    f32x2 acc[4][4];
#pragma unroll
    for (int pi = 0; pi < 4; ++pi)
#pragma unroll
        for (int j = 0; j < 4; ++j) acc[pi][j] = (f32x2){0.f, 0.f};

    for (int c0 = 0; c0 < 256; c0 += 32) {
        __syncthreads();
        {   int cc = t >> 3, pp = (t & 7) * 4;
            *(float4*)&xs[cc][pp] =
                *(const float4*)&x[(size_t)b * 65536 + (size_t)(c0 + cc) * 256 + pix0 + pp];
        }
        {   const float* wr = Wpre + (size_t)t * 256 + c0;
#pragma unroll
            for (int i = 0; i < 32; i += 4) {
                float4 v = *(const float4*)&wr[i];
                wt[i + 0][t] = v.x; wt[i + 1][t] = v.y;
                wt[i + 2][t] = v.z; wt[i + 3][t] = v.w;
            }
        }
        __syncthreads();
#pragma unroll 8
        for (int cc = 0; cc < 32; ++cc) {
            float4 xv = *(const float4*)&xs[cc][pg * 4];
            float xa[4] = {xv.x, xv.y, xv.z, xv.w};
            f32x2 wv[4];
#pragma unroll
            for (int j = 0; j < 4; ++j) wv[j] = *(const f32x2*)&wt[cc][2 * ep + 64 * j];
#pragma unroll
            for (int pi = 0; pi < 4; ++pi) {
                f32x2 xsp = {xa[pi], xa[pi]};
#pragma unroll
                for (int j = 0; j < 4; ++j) {
                    f32x2 m = wv[j] * xsp;       // pk_mul (rounded)
                    acc[pi][j] = acc[pi][j] + m;  // pk_add (rounded) — contract off
                }
            }
        }
    }
    __syncthreads();   // all wt reads done before aliasing writes
    float* zs = &wt[0][0];   // [32][260]
    f32x2 b2[4];
#pragma unroll
    for (int j = 0; j < 4; ++j) b2[j] = *(const f32x2*)&bpre[2 * ep + 64 * j];
#pragma unroll
    for (int pi = 0; pi < 4; ++pi) {
        int row = pg * 4 + pi;
#pragma unroll
        for (int j = 0; j < 4; ++j) {
            f32x2 o = acc[pi][j] + b2[j];
            *(f32x2*)&z32[(size_t)(n0 + row) * 256 + 2 * ep + 64 * j] = o;
            *(f32x2*)&zs[row * 260 + 2 * ep + 64 * j] = o;
        }
    }
    __syncthreads();
#pragma unroll
    for (int q = 0; q < 4; ++q) {
        int uid = q * 256 + t;
        int l = uid & 63, ks = (uid >> 6) & 7, tile = uid >> 9;
        int rowl = tile * 16 + (l & 15), colb = ks * 32 + (l >> 4) * 8;
        const float* s = &zs[rowl * 260 + colb];
        float4 a = *(const float4*)s, bb = *(const float4*)(s + 4);
        u16x8 o;
        o[0] = f2bf(a.x); o[1] = f2bf(a.y); o[2] = f2bf(a.z); o[3] = f2bf(a.w);
        o[4] = f2bf(bb.x); o[5] = f2bf(bb.y); o[6] = f2bf(bb.z); o[7] = f2bf(bb.w);
        *((u16x8*)zbf + (((size_t)((n0 >> 4) + tile) * 8 + ks) * 64 + l)) = o;
    }
    if (t < 32) {
        float a = __fadd_rn(np_sqpair128(&zs[t * 260]), np_sqpair128(&zs[t * 260 + 128]));
        A32[n0 + t] = a;
        thr[n0 + t] = 2.75f * sqrtf(a) * 7.0466e-5f - 1e-6f;
    }
}

// ---------------- cb norms (np pairwise semantics) ----------------
__global__ __launch_bounds__(256) void cb_norms(const float* __restrict__ cb,
                                                float* __restrict__ C32) {
    int v = blockIdx.x * 256 + threadIdx.x;
    const float* r = cb + (size_t)v * 256;
    C32[v] = __fadd_rn(np_sqpair128(r), np_sqpair128(r + 128));
}

// ---------------- fragment-layout bf16 builder (codebook) ----------------
__global__ __launch_bounds__(256) void build_frag(const float* __restrict__ src,
                                                  unsigned short* __restrict__ dst) {
    int gid = blockIdx.x * 256 + threadIdx.x;
    int l = gid & 63, ks = (gid >> 6) & 7, tile = gid >> 9;
    int row = tile * 16 + (l & 15);
    int k = ks * 32 + (l >> 4) * 8;
    const float* s = src + (size_t)row * 256 + k;
    float4 a = *(const float4*)s, b = *(const float4*)(s + 4);
    u16x8 o;
    o[0] = f2bf(a.x); o[1] = f2bf(a.y); o[2] = f2bf(a.z); o[3] = f2bf(a.w);
    o[4] = f2bf(b.x); o[5] = f2bf(b.y); o[6] = f2bf(b.z); o[7] = f2bf(b.w);
    *((u16x8*)dst + gid) = o;
}

// ---------------- Stage 2: MFMA screen v9 (pipelined epilogue) ----------------
// r13 post-mortem: 96us with MfmaUtil=VALUBusy=29% -> dependency-bound tile epilogue:
// in-loop C32 load (exposed L2 latency), aa[4] reg-copy (16 v_mov/tile), 16 divergent
// branch sites/tile. v9: C32 prefetched in the af double-buffer (cpA/cpB); named
// accumulators + per-tt coarse max test (4 branch sites, fine checks in rare path);
// s_setprio(1) around the MFMA burst (waves are free-running -> role diversity).
// Candidate set identical (coarse max passes iff any fine check passes).
#define CHECK_TT(A0, A1, A2, A3, TT)                                                \
    do {                                                                            \
        float s0 = __fmaf_rn(-0.5f, cv0, (A0));                                     \
        float s1 = __fmaf_rn(-0.5f, cv1, (A1));                                     \
        float s2 = __fmaf_rn(-0.5f, cv2, (A2));                                     \
        float s3 = __fmaf_rn(-0.5f, cv3, (A3));                                     \
        float mx = fmaxf(fmaxf(s0, s1), fmaxf(s2, s3));                             \
        if (mx > thrv[TT]) {                                                        \
            float ss[4] = {s0, s1, s2, s3};                                         \
            _Pragma("unroll")                                                       \
            for (int j = 0; j < 4; ++j)                                             \
                if (ss[j] > thrv[TT]) {                                             \
                    int slot = atomicAdd(&wq[w], 1);                                \
                    unsigned pk = ((unsigned)rown[TT] << 13) | (unsigned)(v0 + j);  \
                    if (slot < QCAP) q[w][slot] = pk;                               \
                    else {                                                          \
                        int sl = atomicAdd(&cnt[rown[TT]], 1);                      \
                        if (sl < 64) cand[(size_t)rown[TT] * 64 + sl] = v0 + j;     \
                    }                                                               \
                }                                                                   \
        }                                                                           \
    } while (0)

#define COMPUTE_TILE(AF, CP, TI)                                                    \
    do {                                                                            \
        f32x4 a0 = {0.f,0.f,0.f,0.f}, a1 = {0.f,0.f,0.f,0.f};                       \
        f32x4 a2 = {0.f,0.f,0.f,0.f}, a3 = {0.f,0.f,0.f,0.f};                       \
        __builtin_amdgcn_s_setprio(1);                                              \
        _Pragma("unroll")                                                           \
        for (int ks = 0; ks < 8; ++ks) {                                            \
            a0 = __builtin_amdgcn_mfma_f32_16x16x32_bf16(AF[ks], zf[0][ks], a0,0,0,0); \
            a1 = __builtin_amdgcn_mfma_f32_16x16x32_bf16(AF[ks], zf[1][ks], a1,0,0,0); \
            a2 = __builtin_amdgcn_mfma_f32_16x16x32_bf16(AF[ks], zf[2][ks], a2,0,0,0); \
            a3 = __builtin_amdgcn_mfma_f32_16x16x32_bf16(AF[ks], zf[3][ks], a3,0,0,0); \
        }                                                                           \
        __builtin_amdgcn_s_setprio(0);                                              \
        int v0 = vblk * 1024 + (TI) * 16 + (l >> 4) * 4;                            \
        float cv0 = CP.x, cv1 = CP.y, cv2 = CP.z, cv3 = CP.w;                       \
        CHECK_TT(a0[0], a0[1], a0[2], a0[3], 0);                                    \
        CHECK_TT(a1[0], a1[1], a1[2], a1[3], 1);                                    \
        CHECK_TT(a2[0], a2[1], a2[2], a2[3], 2);                                    \
        CHECK_TT(a3[0], a3[1], a3[2], a3[3], 3);                                    \
    } while (0)

__global__ __launch_bounds__(512) void screen(const unsigned short* __restrict__ zbf,
                                              const unsigned short* __restrict__ cbf,
                                              const float* __restrict__ C32,
                                              const float* __restrict__ thr,
                                              int* __restrict__ cnt,
                                              int* __restrict__ cand) {
    __shared__ unsigned q[8][QCAP];   // 16 KiB per-wave candidate queues
    __shared__ int wq[8];
    int t = threadIdx.x, w = t >> 6, l = t & 63;
    int bid = blockIdx.x;
    int x = bid & 7, k = bid >> 3;
    int rowblk = (x & 3) * 8 + (k & 7);
    int vblk   = (x >> 2) * 4 + (k >> 3);
    int rb = rowblk * 512 + w * 64;

    bf16x8 zf[4][8];
#pragma unroll
    for (int tt = 0; tt < 4; ++tt)
#pragma unroll
        for (int ks = 0; ks < 8; ++ks) {
            zf[tt][ks] = *((const bf16x8*)zbf + (((size_t)((rb >> 4) + tt) * 8 + ks) * 64 + l));
            asm volatile("" : "+a"(zf[tt][ks]));
        }

    int   rown[4];
    float thrv[4];
#pragma unroll
    for (int tt = 0; tt < 4; ++tt) {
        rown[tt] = rb + tt * 16 + (l & 15);
        thrv[tt] = thr[rown[tt]];
    }
    if (t < 8) wq[t] = 0;
    __syncthreads();   // queues ready (only barrier before flush)

    const bf16x8* cb8 = (const bf16x8*)cbf;
    size_t tb = (size_t)(vblk * 64) * 512;   // frag-elems: tile i at tb + i*512 + ks*64 + l
    const float* c32b = C32 + vblk * 1024 + (l >> 4) * 4;

    bf16x8 afA[8], afB[8];
    float4 cpA, cpB;
#pragma unroll
    for (int ks = 0; ks < 8; ++ks)
        afA[ks] = cb8[tb + ks * 64 + l];
    cpA = *(const float4*)&c32b[0];

#pragma unroll 1
    for (int i = 0; i < 64; i += 2) {
        size_t nb = tb + (size_t)(i + 1) * 512;
#pragma unroll
        for (int ks = 0; ks < 8; ++ks)
            afB[ks] = cb8[nb + ks * 64 + l];          // prefetch odd tile
        cpB = *(const float4*)&c32b[(i + 1) * 16];
        COMPUTE_TILE(afA, cpA, i);                     // compute even tile
        if (i < 62) {
            size_t nb2 = tb + (size_t)(i + 2) * 512;
#pragma unroll
            for (int ks = 0; ks < 8; ++ks)
                afA[ks] = cb8[nb2 + ks * 64 + l];      // prefetch next even tile
            cpA = *(const float4*)&c32b[(i + 2) * 16];
        }
        COMPUTE_TILE(afB, cpB, i + 1);                 // compute odd tile
    }
    __syncthreads();

    // per-wave flush: queue -> global (atomic latency exposed once, not per fire)
    int nq = wq[w] < QCAP ? wq[w] : QCAP;
    for (int i = l; i < nq; i += 64) {
        unsigned pk = q[w][i];
        int row = pk >> 13, v = pk & 8191;
        int sl = atomicAdd(&cnt[row], 1);
        if (sl < 64) cand[(size_t)row * 64 + sl] = v;
    }
}

// ---------------- Stage 3: exact np-f32 re-rank v3 ([k][item] LDS, reg-prefetch) ----------------
__global__ __launch_bounds__(256, 3) void rerank(const float* __restrict__ z32,
                                                 const float* __restrict__ cb,
                                                 const float* __restrict__ A32,
                                                 const float* __restrict__ C32,
                                                 const int* __restrict__ cand,
                                                 const int* __restrict__ cnt,
                                                 int* __restrict__ tok_i,
                                                 float* __restrict__ tok_f) {
    __shared__ float    sbuf[32][265];   // [k][item], 33.9 KB
    __shared__ float    zs[8][264];      // z rows, 8.4 KB
    __shared__ unsigned sv[512];         // packed (row<<13)|v
    __shared__ int      sh[9];
    __shared__ float    dbuf[8][64];
    __shared__ int      vbuf[8][64];
    int t = threadIdx.x;
    int n0 = blockIdx.x * 8;

    if (t == 0) {
        int o = 0;
#pragma unroll
        for (int r = 0; r < 8; ++r) {
            sh[r] = o;
            int n = cnt[n0 + r]; if (n > 64) n = 64;
            o += n;
        }
        sh[8] = o;
    }
    {   // stage z rows (coalesced) + init result slots
        int r = t >> 5, e = (t & 31) * 8;
        const float* zr = &z32[(size_t)(n0 + r) * 256 + e];
        *(float4*)&zs[r][e]     = *(const float4*)zr;
        *(float4*)&zs[r][e + 4] = *(const float4*)(zr + 4);
        int sl = t & 31;
        dbuf[r][sl] = 3.4e38f;      dbuf[r][sl + 32] = 3.4e38f;
        vbuf[r][sl] = 0x7fffffff;   vbuf[r][sl + 32] = 0x7fffffff;
    }
    __syncthreads();
    int m = sh[8];

    for (int i = t; i < m; i += 256) {
        int r = 0;
#pragma unroll
        for (int j = 1; j < 8; ++j) r += (i >= sh[j]);
        unsigned v = (unsigned)cand[(size_t)(n0 + r) * 64 + (i - sh[r])];
        sv[i] = ((unsigned)r << 13) | v;
    }
    __syncthreads();

    for (int b0 = 0; b0 < m; b0 += 256) {
        int mb = m - b0; if (mb > 256) mb = 256;
        bool act = t < mb;
        unsigned pk = act ? sv[b0 + t] : 0;
        int myrow = pk >> 13, myv = pk & 8191;
        float s = 0.0f;

        float4 pf[8];
#pragma unroll
        for (int j = 0; j < 8; ++j) {
            int i = j * 32 + (t >> 3);
            if (i < mb) {
                unsigned vv = sv[b0 + i] & 8191u;
                pf[j] = *(const float4*)&cb[(size_t)vv * 256 + (t & 7) * 4];
            }
        }
        for (int c = 0; c < 8; ++c) {
            __syncthreads();   // prior chunk's sbuf reads complete
#pragma unroll
            for (int j = 0; j < 8; ++j) {
                int i = j * 32 + (t >> 3);
                if (i < mb) {
                    int kb = (t & 7) * 4;
                    sbuf[kb + 0][i] = pf[j].x; sbuf[kb + 1][i] = pf[j].y;
                    sbuf[kb + 2][i] = pf[j].z; sbuf[kb + 3][i] = pf[j].w;
                }
            }
            __syncthreads();
            if (c < 7) {   // issue next chunk's loads; latency hides under compute
#pragma unroll
                for (int j = 0; j < 8; ++j) {
                    int i = j * 32 + (t >> 3);
                    if (i < mb) {
                        unsigned vv = sv[b0 + i] & 8191u;
                        pf[j] = *(const float4*)&cb[(size_t)vv * 256 + (c + 1) * 32 + (t & 7) * 4];
                    }
                }
            }
            if (act) {
                const float* zz = &zs[myrow][c * 32];
#pragma unroll
                for (int k = 0; k < 32; ++k)
                    s = __fmaf_rn(sbuf[k][t], zz[k], s);   // ascending k (r2 chain)
            }
        }
        if (act) {
            float d = __fadd_rn(__fsub_rn(A32[n0 + myrow], __fmul_rn(2.0f, s)), C32[myv]);
            int slot = (b0 + t) - sh[myrow];
            dbuf[myrow][slot] = d;
            vbuf[myrow][slot] = myv;
        }
    }
    __syncthreads();
    {   // per-row argmin: 32 threads per row
        int r = t >> 5, l5 = t & 31;
        float d1 = dbuf[r][l5], d2 = dbuf[r][l5 + 32];
        int   v1 = vbuf[r][l5], v2 = vbuf[r][l5 + 32];
        if (d2 < d1 || (d2 == d1 && v2 < v1)) { d1 = d2; v1 = v2; }
#pragma unroll
        for (int off = 16; off > 0; off >>= 1) {
            float dd = __shfl_xor(d1, off, 32);
            int   vv = __shfl_xor(v1, off, 32);
            if (dd < d1 || (dd == d1 && vv < v1)) { d1 = dd; v1 = vv; }
        }
        if (l5 == 0) { tok_i[n0 + r] = v1; tok_f[n0 + r] = (float)v1; }
    }
}

// ---------------- Stage 4: rec = codebook[tok] @ W_post^T + b_post ----------------
__global__ __launch_bounds__(256) void post_quant(const float* __restrict__ cb,
                                                  const float* __restrict__ Wpost,
                                                  const float* __restrict__ bpost,
                                                  const int* __restrict__ tok,
                                                  float* __restrict__ rec) {
    __shared__ float zq[256][36];   // [e][pix]
    __shared__ float wt[32][260];   // [e-chunk][cout]
    int n0 = blockIdx.x * 32;
    int b = n0 >> 8, pix0 = n0 & 255;
    int t = threadIdx.x;
    int ep = t & 31, pg = t >> 5;

    {   int pix = t & 31, eg = t >> 5;
        int tv = tok[n0 + pix];
        const float* cr = cb + (size_t)tv * 256 + eg * 32;
#pragma unroll
        for (int i = 0; i < 32; ++i)
            zq[eg * 32 + i][pix] = cr[i];
    }

    f32x2 acc[8][2];
#pragma unroll
    for (int s = 0; s < 8; ++s) { acc[s][0] = (f32x2){0.f, 0.f}; acc[s][1] = (f32x2){0.f, 0.f}; }

    for (int e0 = 0; e0 < 256; e0 += 32) {
        __syncthreads();
        const float* wr = Wpost + (size_t)t * 256 + e0;
#pragma unroll
        for (int i = 0; i < 32; i += 4) {
            float4 v = *(const float4*)&wr[i];
            wt[i + 0][t] = v.x; wt[i + 1][t] = v.y;
            wt[i + 2][t] = v.z; wt[i + 3][t] = v.w;
        }
        __syncthreads();
#pragma unroll 8
        for (int ee = 0; ee < 32; ++ee) {
            float4 zv = *(const float4*)&zq[e0 + ee][pg * 4];
            f32x2 zp0 = {zv.x, zv.y}, zp1 = {zv.z, zv.w};
#pragma unroll
            for (int J = 0; J < 4; ++J) {
                f32x2 wv = *(const f32x2*)&wt[ee][2 * ep + 64 * J];
                f32x2 w0 = {wv[0], wv[0]}, w1 = {wv[1], wv[1]};
                acc[2 * J + 0][0] = w0 * zp0 + acc[2 * J + 0][0];
                acc[2 * J + 0][1] = w0 * zp1 + acc[2 * J + 0][1];
                acc[2 * J + 1][0] = w1 * zp0 + acc[2 * J + 1][0];
                acc[2 * J + 1][1] = w1 * zp1 + acc[2 * J + 1][1];
            }
        }
    }
#pragma unroll
    for (int J = 0; J < 4; ++J)
#pragma unroll
        for (int c01 = 0; c01 < 2; ++c01) {
            int cout = 2 * ep + 64 * J + c01;
            float bv = bpost[cout];
            f32x2 bs = {bv, bv};
            f32x2 o0 = acc[2 * J + c01][0] + bs, o1 = acc[2 * J + c01][1] + bs;
            float4 ov = {o0[0], o0[1], o1[0], o1[1]};
            *(float4*)&rec[(size_t)b * 65536 + (size_t)cout * 256 + pix0 + pg * 4] = ov;
        }
}

// ---------------- Launch ----------------
extern "C" void kernel_launch(void* const* d_in, const int* in_sizes, int n_in,
                              void* d_out, int out_size, void* d_ws, size_t ws_size,
                              hipStream_t stream) {
    const float* x     = (const float*)d_in[0];
    const float* Wpre  = (const float*)d_in[1];
    const float* bpre  = (const float*)d_in[2];
    const float* cb    = (const float*)d_in[3];
    const float* Wpost = (const float*)d_in[4];
    const float* bpost = (const float*)d_in[5];

    float* out   = (float*)d_out;
    float* rec   = out;
    float* tok_f = out + 4194304;
    float* z32   = rec;   // z lives in rec region until post_quant overwrites it

    char* ws = (char*)d_ws;
    float*          A32   = (float*)(ws + 0);         // 64 KiB
    float*          C32   = (float*)(ws + 65536);     // 32 KiB
    int*            tok_i = (int*)(ws + 98304);       // 64 KiB
    float*          thr   = (float*)(ws + 163840);    // 64 KiB
    int*            cnt   = (int*)(ws + 229376);      // 64 KiB
    int*            cand  = (int*)(ws + 294912);      // 4 MiB
    unsigned short* zbf   = (unsigned short*)(ws + 4489216);   // 8 MiB
    unsigned short* cbf   = (unsigned short*)(ws + 12877824);  // 4 MiB

    pre_quant_fused<<<NPIX / 32, 256, 0, stream>>>(x, Wpre, bpre, z32, zbf, A32, thr);
    cb_norms<<<VDIM / 256, 256, 0, stream>>>(cb, C32);
    build_frag<<<(VDIM / 16) * 8 * 64 / 256, 256, 0, stream>>>(cb, cbf);
    hipMemsetAsync(cnt, 0, NPIX * sizeof(int), stream);
    screen<<<256, 512, 0, stream>>>(zbf, cbf, C32, thr, cnt, cand);
    rerank<<<NPIX / 8, 256, 0, stream>>>(z32, cb, A32, C32, cand, cnt, tok_i, tok_f);
    post_quant<<<NPIX / 32, 256, 0, stream>>>(cb, Wpost, bpost, tok_i, rec);
}

// Round 15
// 251.569 us; speedup vs baseline: 2.1471x; 1.0538x over previous
//
#include <hip/hip_runtime.h>
#include <cstdint>
#include <cstddef>

#define EDIM 256
#define VDIM 8192
#define NPIX 16384
#define QCAP 512

typedef __attribute__((ext_vector_type(8))) short          bf16x8;
typedef __attribute__((ext_vector_type(8))) unsigned short u16x8;
typedef __attribute__((ext_vector_type(4))) float          f32x4;
typedef __attribute__((ext_vector_type(2))) float          f32x2;

// RNE float->bf16
__device__ __forceinline__ unsigned short f2bf(float x) {
    unsigned int u = __float_as_uint(x);
    return (unsigned short)((u + 0x7fffu + ((u >> 16) & 1u)) >> 16);
}

// ---------- numpy pairwise sum-of-squares (exact semantics, verified r2) ----------
__device__ __forceinline__ float np_sqpair128(const float* __restrict__ z) {
    float r[8];
#pragma unroll
    for (int j = 0; j < 8; ++j) r[j] = __fmul_rn(z[j], z[j]);
    for (int i = 8; i < 128; i += 8) {
#pragma unroll
        for (int j = 0; j < 8; ++j)
            r[j] = __fadd_rn(r[j], __fmul_rn(z[i + j], z[i + j]));
    }
    float t01 = __fadd_rn(r[0], r[1]), t23 = __fadd_rn(r[2], r[3]);
    float t45 = __fadd_rn(r[4], r[5]), t67 = __fadd_rn(r[6], r[7]);
    return __fadd_rn(__fadd_rn(t01, t23), __fadd_rn(t45, t67));
}

// ---------------- Stage 1 (FUSED): z32 + zbf frags + A32 + thr ----------------
// r15: T14 async-STAGE — chunk c+1's global loads issued right after the stage
// sync so L2 latency hides under the chunk-c compute. Values/order identical.
__global__ __launch_bounds__(256) void pre_quant_fused(const float* __restrict__ x,
                                                       const float* __restrict__ Wpre,
                                                       const float* __restrict__ bpre,
                                                       float* __restrict__ z32,
                                                       unsigned short* __restrict__ zbf,
                                                       float* __restrict__ A32,
                                                       float* __restrict__ thr) {
#pragma clang fp contract(off)
    __shared__ float xs[32][36];
    __shared__ float wt[32][260];   // [c][e]; aliased as zs[32][260] in epilogue
    int n0 = blockIdx.x * 32;
    int b = n0 >> 8, pix0 = n0 & 255;
    int t = threadIdx.x;
    int ep = t & 31, pg = t >> 5;
    int cc = t >> 3, pp = (t & 7) * 4;   // staging coords

    f32x2 acc[4][4];
#pragma unroll
    for (int pi = 0; pi < 4; ++pi)
#pragma unroll
        for (int j = 0; j < 4; ++j) acc[pi][j] = (f32x2){0.f, 0.f};

    // prologue: issue chunk-0 loads into registers
    float4 xreg = *(const float4*)&x[(size_t)b * 65536 + (size_t)cc * 256 + pix0 + pp];
    float4 wreg[8];
    {
        const float* wr = Wpre + (size_t)t * 256;
#pragma unroll
        for (int i = 0; i < 8; ++i) wreg[i] = *(const float4*)&wr[i * 4];
    }

    for (int c0 = 0; c0 < 256; c0 += 32) {
        __syncthreads();   // previous chunk's compute done reading LDS
        *(float4*)&xs[cc][pp] = xreg;
#pragma unroll
        for (int i = 0; i < 8; ++i) {
            float4 v = wreg[i];
            wt[4 * i + 0][t] = v.x; wt[4 * i + 1][t] = v.y;
            wt[4 * i + 2][t] = v.z; wt[4 * i + 3][t] = v.w;
        }
        __syncthreads();
        if (c0 < 224) {   // issue next chunk's loads; latency hides under compute
            int cn = c0 + 32;
            xreg = *(const float4*)&x[(size_t)b * 65536 + (size_t)(cn + cc) * 256 + pix0 + pp];
            const float* wr = Wpre + (size_t)t * 256 + cn;
#pragma unroll
            for (int i = 0; i < 8; ++i) wreg[i] = *(const float4*)&wr[i * 4];
        }
#pragma unroll 8
        for (int c = 0; c < 32; ++c) {
            float4 xv = *(const float4*)&xs[c][pg * 4];
            float xa[4] = {xv.x, xv.y, xv.z, xv.w};
            f32x2 wv[4];
#pragma unroll
            for (int j = 0; j < 4; ++j) wv[j] = *(const f32x2*)&wt[c][2 * ep + 64 * j];
#pragma unroll
            for (int pi = 0; pi < 4; ++pi) {
                f32x2 xsp = {xa[pi], xa[pi]};
#pragma unroll
                for (int j = 0; j < 4; ++j) {
                    f32x2 m = wv[j] * xsp;       // pk_mul (rounded)
                    acc[pi][j] = acc[pi][j] + m;  // pk_add (rounded) — contract off
                }
            }
        }
    }
    __syncthreads();   // all wt reads done before aliasing writes
    float* zs = &wt[0][0];   // [32][260]
    f32x2 b2[4];
#pragma unroll
    for (int j = 0; j < 4; ++j) b2[j] = *(const f32x2*)&bpre[2 * ep + 64 * j];
#pragma unroll
    for (int pi = 0; pi < 4; ++pi) {
        int row = pg * 4 + pi;
#pragma unroll
        for (int j = 0; j < 4; ++j) {
            f32x2 o = acc[pi][j] + b2[j];
            *(f32x2*)&z32[(size_t)(n0 + row) * 256 + 2 * ep + 64 * j] = o;
            *(f32x2*)&zs[row * 260 + 2 * ep + 64 * j] = o;
        }
    }
    __syncthreads();
#pragma unroll
    for (int q = 0; q < 4; ++q) {
        int uid = q * 256 + t;
        int l = uid & 63, ks = (uid >> 6) & 7, tile = uid >> 9;
        int rowl = tile * 16 + (l & 15), colb = ks * 32 + (l >> 4) * 8;
        const float* s = &zs[rowl * 260 + colb];
        float4 a = *(const float4*)s, bb = *(const float4*)(s + 4);
        u16x8 o;
        o[0] = f2bf(a.x); o[1] = f2bf(a.y); o[2] = f2bf(a.z); o[3] = f2bf(a.w);
        o[4] = f2bf(bb.x); o[5] = f2bf(bb.y); o[6] = f2bf(bb.z); o[7] = f2bf(bb.w);
        *((u16x8*)zbf + (((size_t)((n0 >> 4) + tile) * 8 + ks) * 64 + l)) = o;
    }
    if (t < 32) {
        float a = __fadd_rn(np_sqpair128(&zs[t * 260]), np_sqpair128(&zs[t * 260 + 128]));
        A32[n0 + t] = a;
        thr[n0 + t] = 2.75f * sqrtf(a) * 7.0466e-5f - 1e-6f;
    }
}

// ---------------- cb_prep (FUSED): cbf frags + C32 norms + cnt zeroing ----------------
// Replaces cb_norms + build_frag + hipMemsetAsync(cnt). Norms use 8 threads/row:
// r[h] chains are independent serial chains; the 3-level shfl_xor tree reproduces
// numpy's ((r0+r1)+(r2+r3))+((r4+r5)+(r6+r7)) add order exactly (fadd commutes).
__global__ __launch_bounds__(256) void cb_prep(const float* __restrict__ cb,
                                               unsigned short* __restrict__ cbf,
                                               float* __restrict__ C32,
                                               int* __restrict__ cnt) {
    int t = threadIdx.x;
    int bid = blockIdx.x;
    int r0 = bid * 32;

    if (t < 64) cnt[bid * 64 + t] = 0;   // 256 blocks x 64 = 16384

#pragma unroll
    for (int q = 0; q < 4; ++q) {
        int uid = q * 256 + t;
        int l = uid & 63, ks = (uid >> 6) & 7, tile = uid >> 9;
        int row = r0 + tile * 16 + (l & 15);
        int k = ks * 32 + (l >> 4) * 8;
        const float* s = cb + (size_t)row * 256 + k;
        float4 a = *(const float4*)s, b = *(const float4*)(s + 4);
        u16x8 o;
        o[0] = f2bf(a.x); o[1] = f2bf(a.y); o[2] = f2bf(a.z); o[3] = f2bf(a.w);
        o[4] = f2bf(b.x); o[5] = f2bf(b.y); o[6] = f2bf(b.z); o[7] = f2bf(b.w);
        *((u16x8*)cbf + (((size_t)((r0 >> 4) + tile) * 8 + ks) * 64 + l)) = o;
    }
    {   // numpy-exact pairwise norm, 8 threads per row
        int row = r0 + (t >> 3), h = t & 7;
        const float* a = cb + (size_t)row * 256;
        float rA = __fmul_rn(a[h], a[h]);
        float rB = __fmul_rn(a[128 + h], a[128 + h]);
        for (int i = 8; i < 128; i += 8) {
            rA = __fadd_rn(rA, __fmul_rn(a[i + h], a[i + h]));
            rB = __fadd_rn(rB, __fmul_rn(a[128 + i + h], a[128 + i + h]));
        }
        rA = __fadd_rn(rA, __shfl_xor(rA, 1, 8));
        rB = __fadd_rn(rB, __shfl_xor(rB, 1, 8));
        rA = __fadd_rn(rA, __shfl_xor(rA, 2, 8));
        rB = __fadd_rn(rB, __shfl_xor(rB, 2, 8));
        rA = __fadd_rn(rA, __shfl_xor(rA, 4, 8));
        rB = __fadd_rn(rB, __shfl_xor(rB, 4, 8));
        if (h == 0) C32[row] = __fadd_rn(rA, rB);
    }
}

// ---------------- Stage 2: MFMA screen v9 (r14-validated, unchanged) ----------------
#define CHECK_TT(A0, A1, A2, A3, TT)                                                \
    do {                                                                            \
        float s0 = __fmaf_rn(-0.5f, cv0, (A0));                                     \
        float s1 = __fmaf_rn(-0.5f, cv1, (A1));                                     \
        float s2 = __fmaf_rn(-0.5f, cv2, (A2));                                     \
        float s3 = __fmaf_rn(-0.5f, cv3, (A3));                                     \
        float mx = fmaxf(fmaxf(s0, s1), fmaxf(s2, s3));                             \
        if (mx > thrv[TT]) {                                                        \
            float ss[4] = {s0, s1, s2, s3};                                         \
            _Pragma("unroll")                                                       \
            for (int j = 0; j < 4; ++j)                                             \
                if (ss[j] > thrv[TT]) {                                             \
                    int slot = atomicAdd(&wq[w], 1);                                \
                    unsigned pk = ((unsigned)rown[TT] << 13) | (unsigned)(v0 + j);  \
                    if (slot < QCAP) q[w][slot] = pk;                               \
                    else {                                                          \
                        int sl = atomicAdd(&cnt[rown[TT]], 1);                      \
                        if (sl < 64) cand[(size_t)rown[TT] * 64 + sl] = v0 + j;     \
                    }                                                               \
                }                                                                   \
        }                                                                           \
    } while (0)

#define COMPUTE_TILE(AF, CP, TI)                                                    \
    do {                                                                            \
        f32x4 a0 = {0.f,0.f,0.f,0.f}, a1 = {0.f,0.f,0.f,0.f};                       \
        f32x4 a2 = {0.f,0.f,0.f,0.f}, a3 = {0.f,0.f,0.f,0.f};                       \
        __builtin_amdgcn_s_setprio(1);                                              \
        _Pragma("unroll")                                                           \
        for (int ks = 0; ks < 8; ++ks) {                                            \
            a0 = __builtin_amdgcn_mfma_f32_16x16x32_bf16(AF[ks], zf[0][ks], a0,0,0,0); \
            a1 = __builtin_amdgcn_mfma_f32_16x16x32_bf16(AF[ks], zf[1][ks], a1,0,0,0); \
            a2 = __builtin_amdgcn_mfma_f32_16x16x32_bf16(AF[ks], zf[2][ks], a2,0,0,0); \
            a3 = __builtin_amdgcn_mfma_f32_16x16x32_bf16(AF[ks], zf[3][ks], a3,0,0,0); \
        }                                                                           \
        __builtin_amdgcn_s_setprio(0);                                              \
        int v0 = vblk * 1024 + (TI) * 16 + (l >> 4) * 4;                            \
        float cv0 = CP.x, cv1 = CP.y, cv2 = CP.z, cv3 = CP.w;                       \
        CHECK_TT(a0[0], a0[1], a0[2], a0[3], 0);                                    \
        CHECK_TT(a1[0], a1[1], a1[2], a1[3], 1);                                    \
        CHECK_TT(a2[0], a2[1], a2[2], a2[3], 2);                                    \
        CHECK_TT(a3[0], a3[1], a3[2], a3[3], 3);                                    \
    } while (0)

__global__ __launch_bounds__(512) void screen(const unsigned short* __restrict__ zbf,
                                              const unsigned short* __restrict__ cbf,
                                              const float* __restrict__ C32,
                                              const float* __restrict__ thr,
                                              int* __restrict__ cnt,
                                              int* __restrict__ cand) {
    __shared__ unsigned q[8][QCAP];   // 16 KiB per-wave candidate queues
    __shared__ int wq[8];
    int t = threadIdx.x, w = t >> 6, l = t & 63;
    int bid = blockIdx.x;
    int x = bid & 7, k = bid >> 3;
    int rowblk = (x & 3) * 8 + (k & 7);
    int vblk   = (x >> 2) * 4 + (k >> 3);
    int rb = rowblk * 512 + w * 64;

    bf16x8 zf[4][8];
#pragma unroll
    for (int tt = 0; tt < 4; ++tt)
#pragma unroll
        for (int ks = 0; ks < 8; ++ks) {
            zf[tt][ks] = *((const bf16x8*)zbf + (((size_t)((rb >> 4) + tt) * 8 + ks) * 64 + l));
            asm volatile("" : "+a"(zf[tt][ks]));
        }

    int   rown[4];
    float thrv[4];
#pragma unroll
    for (int tt = 0; tt < 4; ++tt) {
        rown[tt] = rb + tt * 16 + (l & 15);
        thrv[tt] = thr[rown[tt]];
    }
    if (t < 8) wq[t] = 0;
    __syncthreads();   // queues ready (only barrier before flush)

    const bf16x8* cb8 = (const bf16x8*)cbf;
    size_t tb = (size_t)(vblk * 64) * 512;   // frag-elems: tile i at tb + i*512 + ks*64 + l
    const float* c32b = C32 + vblk * 1024 + (l >> 4) * 4;

    bf16x8 afA[8], afB[8];
    float4 cpA, cpB;
#pragma unroll
    for (int ks = 0; ks < 8; ++ks)
        afA[ks] = cb8[tb + ks * 64 + l];
    cpA = *(const float4*)&c32b[0];

#pragma unroll 1
    for (int i = 0; i < 64; i += 2) {
        size_t nb = tb + (size_t)(i + 1) * 512;
#pragma unroll
        for (int ks = 0; ks < 8; ++ks)
            afB[ks] = cb8[nb + ks * 64 + l];          // prefetch odd tile
        cpB = *(const float4*)&c32b[(i + 1) * 16];
        COMPUTE_TILE(afA, cpA, i);                     // compute even tile
        if (i < 62) {
            size_t nb2 = tb + (size_t)(i + 2) * 512;
#pragma unroll
            for (int ks = 0; ks < 8; ++ks)
                afA[ks] = cb8[nb2 + ks * 64 + l];      // prefetch next even tile
            cpA = *(const float4*)&c32b[(i + 2) * 16];
        }
        COMPUTE_TILE(afB, cpB, i + 1);                 // compute odd tile
    }
    __syncthreads();

    // per-wave flush: queue -> global (atomic latency exposed once, not per fire)
    int nq = wq[w] < QCAP ? wq[w] : QCAP;
    for (int i = l; i < nq; i += 64) {
        unsigned pk = q[w][i];
        int row = pk >> 13, v = pk & 8191;
        int sl = atomicAdd(&cnt[row], 1);
        if (sl < 64) cand[(size_t)row * 64 + sl] = v;
    }
}

// ---------------- Stage 3: exact np-f32 re-rank v3 (r14-validated, unchanged) ----------------
__global__ __launch_bounds__(256, 3) void rerank(const float* __restrict__ z32,
                                                 const float* __restrict__ cb,
                                                 const float* __restrict__ A32,
                                                 const float* __restrict__ C32,
                                                 const int* __restrict__ cand,
                                                 const int* __restrict__ cnt,
                                                 int* __restrict__ tok_i,
                                                 float* __restrict__ tok_f) {
    __shared__ float    sbuf[32][265];   // [k][item], 33.9 KB
    __shared__ float    zs[8][264];      // z rows, 8.4 KB
    __shared__ unsigned sv[512];         // packed (row<<13)|v
    __shared__ int      sh[9];
    __shared__ float    dbuf[8][64];
    __shared__ int      vbuf[8][64];
    int t = threadIdx.x;
    int n0 = blockIdx.x * 8;

    if (t == 0) {
        int o = 0;
#pragma unroll
        for (int r = 0; r < 8; ++r) {
            sh[r] = o;
            int n = cnt[n0 + r]; if (n > 64) n = 64;
            o += n;
        }
        sh[8] = o;
    }
    {   // stage z rows (coalesced) + init result slots
        int r = t >> 5, e = (t & 31) * 8;
        const float* zr = &z32[(size_t)(n0 + r) * 256 + e];
        *(float4*)&zs[r][e]     = *(const float4*)zr;
        *(float4*)&zs[r][e + 4] = *(const float4*)(zr + 4);
        int sl = t & 31;
        dbuf[r][sl] = 3.4e38f;      dbuf[r][sl + 32] = 3.4e38f;
        vbuf[r][sl] = 0x7fffffff;   vbuf[r][sl + 32] = 0x7fffffff;
    }
    __syncthreads();
    int m = sh[8];

    for (int i = t; i < m; i += 256) {
        int r = 0;
#pragma unroll
        for (int j = 1; j < 8; ++j) r += (i >= sh[j]);
        unsigned v = (unsigned)cand[(size_t)(n0 + r) * 64 + (i - sh[r])];
        sv[i] = ((unsigned)r << 13) | v;
    }
    __syncthreads();

    for (int b0 = 0; b0 < m; b0 += 256) {
        int mb = m - b0; if (mb > 256) mb = 256;
        bool act = t < mb;
        unsigned pk = act ? sv[b0 + t] : 0;
        int myrow = pk >> 13, myv = pk & 8191;
        float s = 0.0f;

        float4 pf[8];
#pragma unroll
        for (int j = 0; j < 8; ++j) {
            int i = j * 32 + (t >> 3);
            if (i < mb) {
                unsigned vv = sv[b0 + i] & 8191u;
                pf[j] = *(const float4*)&cb[(size_t)vv * 256 + (t & 7) * 4];
            }
        }
        for (int c = 0; c < 8; ++c) {
            __syncthreads();   // prior chunk's sbuf reads complete
#pragma unroll
            for (int j = 0; j < 8; ++j) {
                int i = j * 32 + (t >> 3);
                if (i < mb) {
                    int kb = (t & 7) * 4;
                    sbuf[kb + 0][i] = pf[j].x; sbuf[kb + 1][i] = pf[j].y;
                    sbuf[kb + 2][i] = pf[j].z; sbuf[kb + 3][i] = pf[j].w;
                }
            }
            __syncthreads();
            if (c < 7) {   // issue next chunk's loads; latency hides under compute
#pragma unroll
                for (int j = 0; j < 8; ++j) {
                    int i = j * 32 + (t >> 3);
                    if (i < mb) {
                        unsigned vv = sv[b0 + i] & 8191u;
                        pf[j] = *(const float4*)&cb[(size_t)vv * 256 + (c + 1) * 32 + (t & 7) * 4];
                    }
                }
            }
            if (act) {
                const float* zz = &zs[myrow][c * 32];
#pragma unroll
                for (int k = 0; k < 32; ++k)
                    s = __fmaf_rn(sbuf[k][t], zz[k], s);   // ascending k (r2 chain)
            }
        }
        if (act) {
            float d = __fadd_rn(__fsub_rn(A32[n0 + myrow], __fmul_rn(2.0f, s)), C32[myv]);
            int slot = (b0 + t) - sh[myrow];
            dbuf[myrow][slot] = d;
            vbuf[myrow][slot] = myv;
        }
    }
    __syncthreads();
    {   // per-row argmin: 32 threads per row
        int r = t >> 5, l5 = t & 31;
        float d1 = dbuf[r][l5], d2 = dbuf[r][l5 + 32];
        int   v1 = vbuf[r][l5], v2 = vbuf[r][l5 + 32];
        if (d2 < d1 || (d2 == d1 && v2 < v1)) { d1 = d2; v1 = v2; }
#pragma unroll
        for (int off = 16; off > 0; off >>= 1) {
            float dd = __shfl_xor(d1, off, 32);
            int   vv = __shfl_xor(v1, off, 32);
            if (dd < d1 || (dd == d1 && vv < v1)) { d1 = dd; v1 = vv; }
        }
        if (l5 == 0) { tok_i[n0 + r] = v1; tok_f[n0 + r] = (float)v1; }
    }
}

// ---------------- Stage 4: rec = codebook[tok] @ W_post^T + b_post (unchanged) ----------------
__global__ __launch_bounds__(256) void post_quant(const float* __restrict__ cb,
                                                  const float* __restrict__ Wpost,
                                                  const float* __restrict__ bpost,
                                                  const int* __restrict__ tok,
                                                  float* __restrict__ rec) {
    __shared__ float zq[256][36];   // [e][pix]
    __shared__ float wt[32][260];   // [e-chunk][cout]
    int n0 = blockIdx.x * 32;
    int b = n0 >> 8, pix0 = n0 & 255;
    int t = threadIdx.x;
    int ep = t & 31, pg = t >> 5;

    {   int pix = t & 31, eg = t >> 5;
        int tv = tok[n0 + pix];
        const float* cr = cb + (size_t)tv * 256 + eg * 32;
#pragma unroll
        for (int i = 0; i < 32; ++i)
            zq[eg * 32 + i][pix] = cr[i];
    }

    f32x2 acc[8][2];
#pragma unroll
    for (int s = 0; s < 8; ++s) { acc[s][0] = (f32x2){0.f, 0.f}; acc[s][1] = (f32x2){0.f, 0.f}; }

    for (int e0 = 0; e0 < 256; e0 += 32) {
        __syncthreads();
        const float* wr = Wpost + (size_t)t * 256 + e0;
#pragma unroll
        for (int i = 0; i < 32; i += 4) {
            float4 v = *(const float4*)&wr[i];
            wt[i + 0][t] = v.x; wt[i + 1][t] = v.y;
            wt[i + 2][t] = v.z; wt[i + 3][t] = v.w;
        }
        __syncthreads();
#pragma unroll 8
        for (int ee = 0; ee < 32; ++ee) {
            float4 zv = *(const float4*)&zq[e0 + ee][pg * 4];
            f32x2 zp0 = {zv.x, zv.y}, zp1 = {zv.z, zv.w};
#pragma unroll
            for (int J = 0; J < 4; ++J) {
                f32x2 wv = *(const f32x2*)&wt[ee][2 * ep + 64 * J];
                f32x2 w0 = {wv[0], wv[0]}, w1 = {wv[1], wv[1]};
                acc[2 * J + 0][0] = w0 * zp0 + acc[2 * J + 0][0];
                acc[2 * J + 0][1] = w0 * zp1 + acc[2 * J + 0][1];
                acc[2 * J + 1][0] = w1 * zp0 + acc[2 * J + 1][0];
                acc[2 * J + 1][1] = w1 * zp1 + acc[2 * J + 1][1];
            }
        }
    }
#pragma unroll
    for (int J = 0; J < 4; ++J)
#pragma unroll
        for (int c01 = 0; c01 < 2; ++c01) {
            int cout = 2 * ep + 64 * J + c01;
            float bv = bpost[cout];
            f32x2 bs = {bv, bv};
            f32x2 o0 = acc[2 * J + c01][0] + bs, o1 = acc[2 * J + c01][1] + bs;
            float4 ov = {o0[0], o0[1], o1[0], o1[1]};
            *(float4*)&rec[(size_t)b * 65536 + (size_t)cout * 256 + pix0 + pg * 4] = ov;
        }
}

// ---------------- Launch ----------------
extern "C" void kernel_launch(void* const* d_in, const int* in_sizes, int n_in,
                              void* d_out, int out_size, void* d_ws, size_t ws_size,
                              hipStream_t stream) {
    const float* x     = (const float*)d_in[0];
    const float* Wpre  = (const float*)d_in[1];
    const float* bpre  = (const float*)d_in[2];
    const float* cb    = (const float*)d_in[3];
    const float* Wpost = (const float*)d_in[4];
    const float* bpost = (const float*)d_in[5];

    float* out   = (float*)d_out;
    float* rec   = out;
    float* tok_f = out + 4194304;
    float* z32   = rec;   // z lives in rec region until post_quant overwrites it

    char* ws = (char*)d_ws;
    float*          A32   = (float*)(ws + 0);         // 64 KiB
    float*          C32   = (float*)(ws + 65536);     // 32 KiB
    int*            tok_i = (int*)(ws + 98304);       // 64 KiB
    float*          thr   = (float*)(ws + 163840);    // 64 KiB
    int*            cnt   = (int*)(ws + 229376);      // 64 KiB
    int*            cand  = (int*)(ws + 294912);      // 4 MiB
    unsigned short* zbf   = (unsigned short*)(ws + 4489216);   // 8 MiB
    unsigned short* cbf   = (unsigned short*)(ws + 12877824);  // 4 MiB

    pre_quant_fused<<<NPIX / 32, 256, 0, stream>>>(x, Wpre, bpre, z32, zbf, A32, thr);
    cb_prep<<<VDIM / 32, 256, 0, stream>>>(cb, cbf, C32, cnt);
    screen<<<256, 512, 0, stream>>>(zbf, cbf, C32, thr, cnt, cand);
    rerank<<<NPIX / 8, 256, 0, stream>>>(z32, cb, A32, C32, cand, cnt, tok_i, tok_f);
    post_quant<<<NPIX / 32, 256, 0, stream>>>(cb, Wpost, bpost, tok_i, rec);
}

// Round 16
// 215.264 us; speedup vs baseline: 2.5092x; 1.1687x over previous
//
#include <hip/hip_runtime.h>
#include <cstdint>
#include <cstddef>

#define EDIM 256
#define VDIM 8192
#define NPIX 16384
#define QCAP 512

typedef __attribute__((ext_vector_type(8))) short          bf16x8;
typedef __attribute__((ext_vector_type(8))) unsigned short u16x8;
typedef __attribute__((ext_vector_type(4))) float          f32x4;
typedef __attribute__((ext_vector_type(2))) float          f32x2;

// RNE float->bf16
__device__ __forceinline__ unsigned short f2bf(float x) {
    unsigned int u = __float_as_uint(x);
    return (unsigned short)((u + 0x7fffu + ((u >> 16) & 1u)) >> 16);
}

// ---------- numpy pairwise sum-of-squares (exact semantics, verified r2) ----------
__device__ __forceinline__ float np_sqpair128(const float* __restrict__ z) {
    float r[8];
#pragma unroll
    for (int j = 0; j < 8; ++j) r[j] = __fmul_rn(z[j], z[j]);
    for (int i = 8; i < 128; i += 8) {
#pragma unroll
        for (int j = 0; j < 8; ++j)
            r[j] = __fadd_rn(r[j], __fmul_rn(z[i + j], z[i + j]));
    }
    float t01 = __fadd_rn(r[0], r[1]), t23 = __fadd_rn(r[2], r[3]);
    float t45 = __fadd_rn(r[4], r[5]), t67 = __fadd_rn(r[6], r[7]);
    return __fadd_rn(__fadd_rn(t01, t23), __fadd_rn(t45, t67));
}

// ---------------- Stage 1 (FUSED): z32 + zbf frags + A32 + thr (r15-validated) ----------------
__global__ __launch_bounds__(256) void pre_quant_fused(const float* __restrict__ x,
                                                       const float* __restrict__ Wpre,
                                                       const float* __restrict__ bpre,
                                                       float* __restrict__ z32,
                                                       unsigned short* __restrict__ zbf,
                                                       float* __restrict__ A32,
                                                       float* __restrict__ thr) {
#pragma clang fp contract(off)
    __shared__ float xs[32][36];
    __shared__ float wt[32][260];   // [c][e]; aliased as zs[32][260] in epilogue
    int n0 = blockIdx.x * 32;
    int b = n0 >> 8, pix0 = n0 & 255;
    int t = threadIdx.x;
    int ep = t & 31, pg = t >> 5;
    int cc = t >> 3, pp = (t & 7) * 4;   // staging coords

    f32x2 acc[4][4];
#pragma unroll
    for (int pi = 0; pi < 4; ++pi)
#pragma unroll
        for (int j = 0; j < 4; ++j) acc[pi][j] = (f32x2){0.f, 0.f};

    float4 xreg = *(const float4*)&x[(size_t)b * 65536 + (size_t)cc * 256 + pix0 + pp];
    float4 wreg[8];
    {
        const float* wr = Wpre + (size_t)t * 256;
#pragma unroll
        for (int i = 0; i < 8; ++i) wreg[i] = *(const float4*)&wr[i * 4];
    }

    for (int c0 = 0; c0 < 256; c0 += 32) {
        __syncthreads();
        *(float4*)&xs[cc][pp] = xreg;
#pragma unroll
        for (int i = 0; i < 8; ++i) {
            float4 v = wreg[i];
            wt[4 * i + 0][t] = v.x; wt[4 * i + 1][t] = v.y;
            wt[4 * i + 2][t] = v.z; wt[4 * i + 3][t] = v.w;
        }
        __syncthreads();
        if (c0 < 224) {
            int cn = c0 + 32;
            xreg = *(const float4*)&x[(size_t)b * 65536 + (size_t)(cn + cc) * 256 + pix0 + pp];
            const float* wr = Wpre + (size_t)t * 256 + cn;
#pragma unroll
            for (int i = 0; i < 8; ++i) wreg[i] = *(const float4*)&wr[i * 4];
        }
#pragma unroll 8
        for (int c = 0; c < 32; ++c) {
            float4 xv = *(const float4*)&xs[c][pg * 4];
            float xa[4] = {xv.x, xv.y, xv.z, xv.w};
            f32x2 wv[4];
#pragma unroll
            for (int j = 0; j < 4; ++j) wv[j] = *(const f32x2*)&wt[c][2 * ep + 64 * j];
#pragma unroll
            for (int pi = 0; pi < 4; ++pi) {
                f32x2 xsp = {xa[pi], xa[pi]};
#pragma unroll
                for (int j = 0; j < 4; ++j) {
                    f32x2 m = wv[j] * xsp;       // pk_mul (rounded)
                    acc[pi][j] = acc[pi][j] + m;  // pk_add (rounded) — contract off
                }
            }
        }
    }
    __syncthreads();
    float* zs = &wt[0][0];   // [32][260]
    f32x2 b2[4];
#pragma unroll
    for (int j = 0; j < 4; ++j) b2[j] = *(const f32x2*)&bpre[2 * ep + 64 * j];
#pragma unroll
    for (int pi = 0; pi < 4; ++pi) {
        int row = pg * 4 + pi;
#pragma unroll
        for (int j = 0; j < 4; ++j) {
            f32x2 o = acc[pi][j] + b2[j];
            *(f32x2*)&z32[(size_t)(n0 + row) * 256 + 2 * ep + 64 * j] = o;
            *(f32x2*)&zs[row * 260 + 2 * ep + 64 * j] = o;
        }
    }
    __syncthreads();
#pragma unroll
    for (int q = 0; q < 4; ++q) {
        int uid = q * 256 + t;
        int l = uid & 63, ks = (uid >> 6) & 7, tile = uid >> 9;
        int rowl = tile * 16 + (l & 15), colb = ks * 32 + (l >> 4) * 8;
        const float* s = &zs[rowl * 260 + colb];
        float4 a = *(const float4*)s, bb = *(const float4*)(s + 4);
        u16x8 o;
        o[0] = f2bf(a.x); o[1] = f2bf(a.y); o[2] = f2bf(a.z); o[3] = f2bf(a.w);
        o[4] = f2bf(bb.x); o[5] = f2bf(bb.y); o[6] = f2bf(bb.z); o[7] = f2bf(bb.w);
        *((u16x8*)zbf + (((size_t)((n0 >> 4) + tile) * 8 + ks) * 64 + l)) = o;
    }
    if (t < 32) {
        float a = __fadd_rn(np_sqpair128(&zs[t * 260]), np_sqpair128(&zs[t * 260 + 128]));
        A32[n0 + t] = a;
        thr[n0 + t] = 2.75f * sqrtf(a) * 7.0466e-5f - 1e-6f;
    }
}

// ---------------- cb_prep (FUSED): cbf frags + C32 norms + cnt zeroing (r15-validated) ----------------
__global__ __launch_bounds__(256) void cb_prep(const float* __restrict__ cb,
                                               unsigned short* __restrict__ cbf,
                                               float* __restrict__ C32,
                                               int* __restrict__ cnt) {
    int t = threadIdx.x;
    int bid = blockIdx.x;
    int r0 = bid * 32;

    if (t < 64) cnt[bid * 64 + t] = 0;

#pragma unroll
    for (int q = 0; q < 4; ++q) {
        int uid = q * 256 + t;
        int l = uid & 63, ks = (uid >> 6) & 7, tile = uid >> 9;
        int row = r0 + tile * 16 + (l & 15);
        int k = ks * 32 + (l >> 4) * 8;
        const float* s = cb + (size_t)row * 256 + k;
        float4 a = *(const float4*)s, b = *(const float4*)(s + 4);
        u16x8 o;
        o[0] = f2bf(a.x); o[1] = f2bf(a.y); o[2] = f2bf(a.z); o[3] = f2bf(a.w);
        o[4] = f2bf(b.x); o[5] = f2bf(b.y); o[6] = f2bf(b.z); o[7] = f2bf(b.w);
        *((u16x8*)cbf + (((size_t)((r0 >> 4) + tile) * 8 + ks) * 64 + l)) = o;
    }
    {
        int row = r0 + (t >> 3), h = t & 7;
        const float* a = cb + (size_t)row * 256;
        float rA = __fmul_rn(a[h], a[h]);
        float rB = __fmul_rn(a[128 + h], a[128 + h]);
        for (int i = 8; i < 128; i += 8) {
            rA = __fadd_rn(rA, __fmul_rn(a[i + h], a[i + h]));
            rB = __fadd_rn(rB, __fmul_rn(a[128 + i + h], a[128 + i + h]));
        }
        rA = __fadd_rn(rA, __shfl_xor(rA, 1, 8));
        rB = __fadd_rn(rB, __shfl_xor(rB, 1, 8));
        rA = __fadd_rn(rA, __shfl_xor(rA, 2, 8));
        rB = __fadd_rn(rB, __shfl_xor(rB, 2, 8));
        rA = __fadd_rn(rA, __shfl_xor(rA, 4, 8));
        rB = __fadd_rn(rB, __shfl_xor(rB, 4, 8));
        if (h == 0) C32[row] = __fadd_rn(rA, rB);
    }
}

// ---------------- Stage 2: MFMA screen v10 (r14 structure + score-carrying queues) ----------------
// r16: queue entries carry (pk, f32 score) so rerank can prune to candidates within
// eps of the per-row max screen score (provably contains the np-f32 argmin winner).
#define CHECK_TT(A0, A1, A2, A3, TT)                                                \
    do {                                                                            \
        float s0 = __fmaf_rn(-0.5f, cv0, (A0));                                     \
        float s1 = __fmaf_rn(-0.5f, cv1, (A1));                                     \
        float s2 = __fmaf_rn(-0.5f, cv2, (A2));                                     \
        float s3 = __fmaf_rn(-0.5f, cv3, (A3));                                     \
        float mx = fmaxf(fmaxf(s0, s1), fmaxf(s2, s3));                             \
        if (mx > thrv[TT]) {                                                        \
            float ss[4] = {s0, s1, s2, s3};                                         \
            _Pragma("unroll")                                                       \
            for (int j = 0; j < 4; ++j)                                             \
                if (ss[j] > thrv[TT]) {                                             \
                    int slot = atomicAdd(&wq[w], 1);                                \
                    unsigned pk = ((unsigned)rown[TT] << 13) | (unsigned)(v0 + j);  \
                    if (slot < QCAP) { q[w][slot] = pk; qs[w][slot] = ss[j]; }      \
                    else {                                                          \
                        int sl = atomicAdd(&cnt[rown[TT]], 1);                      \
                        if (sl < 64) {                                              \
                            cand[(size_t)rown[TT] * 64 + sl] = v0 + j;              \
                            scr[(size_t)rown[TT] * 64 + sl] = ss[j];                \
                        }                                                           \
                    }                                                               \
                }                                                                   \
        }                                                                           \
    } while (0)

#define COMPUTE_TILE(AF, CP, TI)                                                    \
    do {                                                                            \
        f32x4 a0 = {0.f,0.f,0.f,0.f}, a1 = {0.f,0.f,0.f,0.f};                       \
        f32x4 a2 = {0.f,0.f,0.f,0.f}, a3 = {0.f,0.f,0.f,0.f};                       \
        __builtin_amdgcn_s_setprio(1);                                              \
        _Pragma("unroll")                                                           \
        for (int ks = 0; ks < 8; ++ks) {                                            \
            a0 = __builtin_amdgcn_mfma_f32_16x16x32_bf16(AF[ks], zf[0][ks], a0,0,0,0); \
            a1 = __builtin_amdgcn_mfma_f32_16x16x32_bf16(AF[ks], zf[1][ks], a1,0,0,0); \
            a2 = __builtin_amdgcn_mfma_f32_16x16x32_bf16(AF[ks], zf[2][ks], a2,0,0,0); \
            a3 = __builtin_amdgcn_mfma_f32_16x16x32_bf16(AF[ks], zf[3][ks], a3,0,0,0); \
        }                                                                           \
        __builtin_amdgcn_s_setprio(0);                                              \
        int v0 = vblk * 1024 + (TI) * 16 + (l >> 4) * 4;                            \
        float cv0 = CP.x, cv1 = CP.y, cv2 = CP.z, cv3 = CP.w;                       \
        CHECK_TT(a0[0], a0[1], a0[2], a0[3], 0);                                    \
        CHECK_TT(a1[0], a1[1], a1[2], a1[3], 1);                                    \
        CHECK_TT(a2[0], a2[1], a2[2], a2[3], 2);                                    \
        CHECK_TT(a3[0], a3[1], a3[2], a3[3], 3);                                    \
    } while (0)

__global__ __launch_bounds__(512) void screen(const unsigned short* __restrict__ zbf,
                                              const unsigned short* __restrict__ cbf,
                                              const float* __restrict__ C32,
                                              const float* __restrict__ thr,
                                              int* __restrict__ cnt,
                                              int* __restrict__ cand,
                                              float* __restrict__ scr) {
    __shared__ unsigned q[8][QCAP];    // 16 KiB
    __shared__ float    qs[8][QCAP];   // 16 KiB scores
    __shared__ int wq[8];
    int t = threadIdx.x, w = t >> 6, l = t & 63;
    int bid = blockIdx.x;
    int x = bid & 7, k = bid >> 3;
    int rowblk = (x & 3) * 8 + (k & 7);
    int vblk   = (x >> 2) * 4 + (k >> 3);
    int rb = rowblk * 512 + w * 64;

    bf16x8 zf[4][8];
#pragma unroll
    for (int tt = 0; tt < 4; ++tt)
#pragma unroll
        for (int ks = 0; ks < 8; ++ks) {
            zf[tt][ks] = *((const bf16x8*)zbf + (((size_t)((rb >> 4) + tt) * 8 + ks) * 64 + l));
            asm volatile("" : "+a"(zf[tt][ks]));
        }

    int   rown[4];
    float thrv[4];
#pragma unroll
    for (int tt = 0; tt < 4; ++tt) {
        rown[tt] = rb + tt * 16 + (l & 15);
        thrv[tt] = thr[rown[tt]];
    }
    if (t < 8) wq[t] = 0;
    __syncthreads();

    const bf16x8* cb8 = (const bf16x8*)cbf;
    size_t tb = (size_t)(vblk * 64) * 512;
    const float* c32b = C32 + vblk * 1024 + (l >> 4) * 4;

    bf16x8 afA[8], afB[8];
    float4 cpA, cpB;
#pragma unroll
    for (int ks = 0; ks < 8; ++ks)
        afA[ks] = cb8[tb + ks * 64 + l];
    cpA = *(const float4*)&c32b[0];

#pragma unroll 1
    for (int i = 0; i < 64; i += 2) {
        size_t nb = tb + (size_t)(i + 1) * 512;
#pragma unroll
        for (int ks = 0; ks < 8; ++ks)
            afB[ks] = cb8[nb + ks * 64 + l];
        cpB = *(const float4*)&c32b[(i + 1) * 16];
        COMPUTE_TILE(afA, cpA, i);
        if (i < 62) {
            size_t nb2 = tb + (size_t)(i + 2) * 512;
#pragma unroll
            for (int ks = 0; ks < 8; ++ks)
                afA[ks] = cb8[nb2 + ks * 64 + l];
            cpA = *(const float4*)&c32b[(i + 2) * 16];
        }
        COMPUTE_TILE(afB, cpB, i + 1);
    }
    __syncthreads();

    int nq = wq[w] < QCAP ? wq[w] : QCAP;
    for (int i = l; i < nq; i += 64) {
        unsigned pk = q[w][i];
        int row = pk >> 13, v = pk & 8191;
        int sl = atomicAdd(&cnt[row], 1);
        if (sl < 64) {
            cand[(size_t)row * 64 + sl] = v;
            scr[(size_t)row * 64 + sl] = qs[w][i];
        }
    }
}

// ---------------- Stage 3: re-rank v4 (score-pruned; exact np-f32 chain on survivors) ----------------
// Prune: keep candidates with screen score >= smax_row - eps, eps = 0.25*sigma + 1e-4
// (covers 2x worst bf16-screen error ~7.8e-5 + 2x f32-d rounding ~6e-5 with margin).
// Survivor set provably contains the np-f32 argmin (incl. ties). E[survivors] ~2.3/row.
__global__ __launch_bounds__(256, 3) void rerank(const float* __restrict__ z32,
                                                 const float* __restrict__ cb,
                                                 const float* __restrict__ A32,
                                                 const float* __restrict__ C32,
                                                 const int* __restrict__ cand,
                                                 const float* __restrict__ scr,
                                                 const int* __restrict__ cnt,
                                                 int* __restrict__ tok_i,
                                                 float* __restrict__ tok_f) {
    __shared__ float    sbuf[32][265];   // [k][item] gather buffer
    __shared__ float    zs[8][264];      // z rows
    __shared__ unsigned sv[256];         // packed survivors (row<<13)|v
    __shared__ int      svrow[8][32];
    __shared__ int      nc[8];
    __shared__ int      sh[9];
    __shared__ float    dbuf[8][32];
    __shared__ int      vbuf[8][32];
    int t = threadIdx.x;
    int n0 = blockIdx.x * 8;
    int r = t >> 5, l5 = t & 31;

    {   // stage z rows (coalesced) + init
        int e = l5 * 8;
        const float* zr = &z32[(size_t)(n0 + r) * 256 + e];
        *(float4*)&zs[r][e]     = *(const float4*)zr;
        *(float4*)&zs[r][e + 4] = *(const float4*)(zr + 4);
        dbuf[r][l5] = 3.4e38f;
        vbuf[r][l5] = 0x7fffffff;
        if (l5 == 0) nc[r] = 0;
    }
    __syncthreads();

    // phase 1: per-row smax + prune (coalesced cand/scr reads, shfl max)
    {
        int n = cnt[n0 + r]; if (n > 64) n = 64;
        int cv1 = -1, cv2 = -1; float s1 = -3.4e38f, s2 = -3.4e38f;
        if (l5 < n)      { cv1 = cand[(size_t)(n0 + r) * 64 + l5];      s1 = scr[(size_t)(n0 + r) * 64 + l5]; }
        if (l5 + 32 < n) { cv2 = cand[(size_t)(n0 + r) * 64 + l5 + 32]; s2 = scr[(size_t)(n0 + r) * 64 + l5 + 32]; }
        float smax = fmaxf(s1, s2);
#pragma unroll
        for (int off = 16; off > 0; off >>= 1)
            smax = fmaxf(smax, __shfl_xor(smax, off, 32));
        float sig = sqrtf(A32[n0 + r]) * 7.0466e-5f;
        float cut = smax - __fmaf_rn(0.25f, sig, 1e-4f);
        if (cv1 >= 0 && s1 >= cut) { int p = atomicAdd(&nc[r], 1); if (p < 32) svrow[r][p] = cv1; }
        if (cv2 >= 0 && s2 >= cut) { int p = atomicAdd(&nc[r], 1); if (p < 32) svrow[r][p] = cv2; }
    }
    __syncthreads();
    if (t == 0) {
        int o = 0;
#pragma unroll
        for (int rr = 0; rr < 8; ++rr) {
            sh[rr] = o;
            int c = nc[rr]; if (c > 32) c = 32;
            o += c;
        }
        sh[8] = o;
    }
    __syncthreads();
    int m = sh[8];
    for (int i = t; i < m; i += 256) {
        int rr = 0;
#pragma unroll
        for (int j = 1; j < 8; ++j) rr += (i >= sh[j]);
        sv[i] = ((unsigned)rr << 13) | (unsigned)svrow[rr][i - sh[rr]];
    }
    __syncthreads();

    // phase 2: exact np-f32 dots for survivors (r14-validated chunked gather + chain)
    {
        bool act = t < m;
        unsigned pk = act ? sv[t] : 0;
        int myrow = pk >> 13, myv = pk & 8191;
        float s = 0.0f;
        int gi = t >> 3, gq = t & 7;

        float4 pf[8];
#pragma unroll
        for (int j = 0; j < 8; ++j) {
            int i = j * 32 + gi;
            if (i < m) pf[j] = *(const float4*)&cb[(size_t)(sv[i] & 8191u) * 256 + gq * 4];
        }
        for (int c = 0; c < 8; ++c) {
            __syncthreads();
#pragma unroll
            for (int j = 0; j < 8; ++j) {
                int i = j * 32 + gi;
                if (i < m) {
                    int kb = gq * 4;
                    sbuf[kb + 0][i] = pf[j].x; sbuf[kb + 1][i] = pf[j].y;
                    sbuf[kb + 2][i] = pf[j].z; sbuf[kb + 3][i] = pf[j].w;
                }
            }
            __syncthreads();
            if (c < 7) {
#pragma unroll
                for (int j = 0; j < 8; ++j) {
                    int i = j * 32 + gi;
                    if (i < m)
                        pf[j] = *(const float4*)&cb[(size_t)(sv[i] & 8191u) * 256 + (c + 1) * 32 + gq * 4];
                }
            }
            if (act) {
                const float* zz = &zs[myrow][c * 32];
#pragma unroll
                for (int k = 0; k < 32; ++k)
                    s = __fmaf_rn(sbuf[k][t], zz[k], s);   // strictly ascending k (r2 chain)
            }
        }
        if (act) {
            float d = __fadd_rn(__fsub_rn(A32[n0 + myrow], __fmul_rn(2.0f, s)), C32[myv]);
            int slot = t - sh[myrow];
            dbuf[myrow][slot] = d;
            vbuf[myrow][slot] = myv;
        }
    }
    __syncthreads();
    {   // per-row argmin over 32 slots (d, then index — deterministic over the set)
        float d1 = dbuf[r][l5];
        int   v1 = vbuf[r][l5];
#pragma unroll
        for (int off = 16; off > 0; off >>= 1) {
            float dd = __shfl_xor(d1, off, 32);
            int   vv = __shfl_xor(v1, off, 32);
            if (dd < d1 || (dd == d1 && vv < v1)) { d1 = dd; v1 = vv; }
        }
        if (l5 == 0) { tok_i[n0 + r] = v1; tok_f[n0 + r] = (float)v1; }
    }
}

// ---------------- Stage 4: rec = codebook[tok] @ W_post^T + b_post (unchanged) ----------------
__global__ __launch_bounds__(256) void post_quant(const float* __restrict__ cb,
                                                  const float* __restrict__ Wpost,
                                                  const float* __restrict__ bpost,
                                                  const int* __restrict__ tok,
                                                  float* __restrict__ rec) {
    __shared__ float zq[256][36];   // [e][pix]
    __shared__ float wt[32][260];   // [e-chunk][cout]
    int n0 = blockIdx.x * 32;
    int b = n0 >> 8, pix0 = n0 & 255;
    int t = threadIdx.x;
    int ep = t & 31, pg = t >> 5;

    {   int pix = t & 31, eg = t >> 5;
        int tv = tok[n0 + pix];
        const float* cr = cb + (size_t)tv * 256 + eg * 32;
#pragma unroll
        for (int i = 0; i < 32; ++i)
            zq[eg * 32 + i][pix] = cr[i];
    }

    f32x2 acc[8][2];
#pragma unroll
    for (int s = 0; s < 8; ++s) { acc[s][0] = (f32x2){0.f, 0.f}; acc[s][1] = (f32x2){0.f, 0.f}; }

    for (int e0 = 0; e0 < 256; e0 += 32) {
        __syncthreads();
        const float* wr = Wpost + (size_t)t * 256 + e0;
#pragma unroll
        for (int i = 0; i < 32; i += 4) {
            float4 v = *(const float4*)&wr[i];
            wt[i + 0][t] = v.x; wt[i + 1][t] = v.y;
            wt[i + 2][t] = v.z; wt[i + 3][t] = v.w;
        }
        __syncthreads();
#pragma unroll 8
        for (int ee = 0; ee < 32; ++ee) {
            float4 zv = *(const float4*)&zq[e0 + ee][pg * 4];
            f32x2 zp0 = {zv.x, zv.y}, zp1 = {zv.z, zv.w};
#pragma unroll
            for (int J = 0; J < 4; ++J) {
                f32x2 wv = *(const f32x2*)&wt[ee][2 * ep + 64 * J];
                f32x2 w0 = {wv[0], wv[0]}, w1 = {wv[1], wv[1]};
                acc[2 * J + 0][0] = w0 * zp0 + acc[2 * J + 0][0];
                acc[2 * J + 0][1] = w0 * zp1 + acc[2 * J + 0][1];
                acc[2 * J + 1][0] = w1 * zp0 + acc[2 * J + 1][0];
                acc[2 * J + 1][1] = w1 * zp1 + acc[2 * J + 1][1];
            }
        }
    }
#pragma unroll
    for (int J = 0; J < 4; ++J)
#pragma unroll
        for (int c01 = 0; c01 < 2; ++c01) {
            int cout = 2 * ep + 64 * J + c01;
            float bv = bpost[cout];
            f32x2 bs = {bv, bv};
            f32x2 o0 = acc[2 * J + c01][0] + bs, o1 = acc[2 * J + c01][1] + bs;
            float4 ov = {o0[0], o0[1], o1[0], o1[1]};
            *(float4*)&rec[(size_t)b * 65536 + (size_t)cout * 256 + pix0 + pg * 4] = ov;
        }
}

// ---------------- Launch ----------------
extern "C" void kernel_launch(void* const* d_in, const int* in_sizes, int n_in,
                              void* d_out, int out_size, void* d_ws, size_t ws_size,
                              hipStream_t stream) {
    const float* x     = (const float*)d_in[0];
    const float* Wpre  = (const float*)d_in[1];
    const float* bpre  = (const float*)d_in[2];
    const float* cb    = (const float*)d_in[3];
    const float* Wpost = (const float*)d_in[4];
    const float* bpost = (const float*)d_in[5];

    float* out   = (float*)d_out;
    float* rec   = out;
    float* tok_f = out + 4194304;
    float* z32   = rec;   // z lives in rec region until post_quant overwrites it

    char* ws = (char*)d_ws;
    float*          A32   = (float*)(ws + 0);          // 64 KiB
    float*          C32   = (float*)(ws + 65536);      // 32 KiB
    int*            tok_i = (int*)(ws + 98304);        // 64 KiB
    float*          thr   = (float*)(ws + 163840);     // 64 KiB
    int*            cnt   = (int*)(ws + 229376);       // 64 KiB
    int*            cand  = (int*)(ws + 294912);       // 4 MiB
    unsigned short* zbf   = (unsigned short*)(ws + 4489216);   // 8 MiB
    unsigned short* cbf   = (unsigned short*)(ws + 12877824);  // 4 MiB
    float*          scr   = (float*)(ws + 17072128);   // 4 MiB

    pre_quant_fused<<<NPIX / 32, 256, 0, stream>>>(x, Wpre, bpre, z32, zbf, A32, thr);
    cb_prep<<<VDIM / 32, 256, 0, stream>>>(cb, cbf, C32, cnt);
    screen<<<256, 512, 0, stream>>>(zbf, cbf, C32, thr, cnt, cand, scr);
    rerank<<<NPIX / 8, 256, 0, stream>>>(z32, cb, A32, C32, cand, scr, cnt, tok_i, tok_f);
    post_quant<<<NPIX / 32, 256, 0, stream>>>(cb, Wpost, bpost, tok_i, rec);
}